// Round 2
// baseline (1135.845 us; speedup 1.0000x reference)
//
#include <hip/hip_runtime.h>

#define N_NODES 256
#define COND    64
#define E_PAIRS 32640
#define OUTCOLS 65280
#define BATCH   512
#define SLOTS   576    // 9 row-tiles of 64 (big rows padded to 64, then small, then pad)
#define D1      256
#define D2      512
#define D3      1024

// ---------------- kernel 0: sort rows by expert mask into 64-aligned slots ----
__global__ void k0_sort(const float* __restrict__ x, int* __restrict__ meta,
                        int* __restrict__ borig) {
    __shared__ int mask[BATCH];
    __shared__ int bor[SLOTS];
    int t = threadIdx.x;                 // blockDim = 576
    if (t < SLOTS) bor[t] = -1;
    if (t < BATCH) mask[t] = (x[t * COND] > 0.0f) ? 1 : 0;
    __syncthreads();
    if (t == 0) {
        int nbig = 0;
        for (int b = 0; b < BATCH; ++b) nbig += mask[b];
        int S = (nbig + 63) & ~63;       // big slots [0,S), small [S, S+nsmall)
        int ib = 0, is = S;
        for (int b = 0; b < BATCH; ++b) {
            if (mask[b]) bor[ib++] = b; else bor[is++] = b;
        }
        meta[0] = S;
    }
    __syncthreads();
    if (t < SLOTS) borig[t] = bor[t];
}

// ---------------- kernel 1: per-row 3-layer MLP -> hidden h[slot][1024] -------
__global__ __launch_bounds__(256) void k1_mlp(
    const float* __restrict__ x,
    const float* __restrict__ bw0, const float* __restrict__ bb0,
    const float* __restrict__ sw0, const float* __restrict__ sb0,
    const float* __restrict__ bw1, const float* __restrict__ bb1,
    const float* __restrict__ sw1, const float* __restrict__ sb1,
    const float* __restrict__ bw2, const float* __restrict__ bb2,
    const float* __restrict__ sw2, const float* __restrict__ sb2,
    const int* __restrict__ borig, float* __restrict__ hbuf) {
    __shared__ float xs[COND];
    __shared__ float h1[D1];
    __shared__ float h2[D2];
    int s = blockIdx.x, t = threadIdx.x;
    int b = borig[s];
    if (b < 0) {                          // pad slot: zero hidden row
        for (int c = t; c < D3; c += 256) hbuf[s * D3 + c] = 0.0f;
        return;
    }
    bool big = x[b * COND] > 0.0f;
    const float* w0 = big ? bw0 : sw0;  const float* b0 = big ? bb0 : sb0;
    const float* w1 = big ? bw1 : sw1;  const float* b1 = big ? bb1 : sb1;
    const float* w2 = big ? bw2 : sw2;  const float* b2 = big ? bb2 : sb2;
    if (t < COND) xs[t] = x[b * COND + t];
    __syncthreads();
    // layer 0: 64 -> 256
    {
        float acc = 0.f;
        #pragma unroll 8
        for (int k = 0; k < COND; ++k) acc = fmaf(xs[k], w0[k * D1 + t], acc);
        h1[t] = fmaxf(acc + b0[t], 0.f);
    }
    __syncthreads();
    // layer 1: 256 -> 512
    {
        float a0 = 0.f, a1 = 0.f;
        #pragma unroll 4
        for (int k = 0; k < D1; ++k) {
            float hv = h1[k];
            a0 = fmaf(hv, w1[k * D2 + t], a0);
            a1 = fmaf(hv, w1[k * D2 + t + 256], a1);
        }
        h2[t]       = fmaxf(a0 + b1[t], 0.f);
        h2[t + 256] = fmaxf(a1 + b1[t + 256], 0.f);
    }
    __syncthreads();
    // layer 2: 512 -> 1024, write to global
    {
        float a0 = 0.f, a1 = 0.f, a2 = 0.f, a3 = 0.f;
        #pragma unroll 4
        for (int k = 0; k < D2; ++k) {
            float hv = h2[k];
            a0 = fmaf(hv, w2[k * D3 + t], a0);
            a1 = fmaf(hv, w2[k * D3 + t + 256], a1);
            a2 = fmaf(hv, w2[k * D3 + t + 512], a2);
            a3 = fmaf(hv, w2[k * D3 + t + 768], a3);
        }
        hbuf[s * D3 + t]       = fmaxf(a0 + b2[t], 0.f);
        hbuf[s * D3 + t + 256] = fmaxf(a1 + b2[t + 256], 0.f);
        hbuf[s * D3 + t + 512] = fmaxf(a2 + b2[t + 512], 0.f);
        hbuf[s * D3 + t + 768] = fmaxf(a3 + b2[t + 768], 0.f);
    }
}

// ---------------- kernel 2: fp32 DIFFERENCE-GEMM (slots x 32640 e-pairs) ------
// Register-prefetched main loop: globals for tile k+1 issue BEFORE the 16-kk
// compute of tile k, hiding HBM/L2 latency under ~1024 VALU cycles. Inner loop
// written with explicit float4 components (no local arrays -> no v_mov copies).
// SQ=true: epilogue scatters bits into padded square [b][256][256] layout
// (aligned rows) via exact closed-form e->(i,j); SQ=false: packed triangular.
#define BM   64
#define BNW  256   // w3 columns per block (= 128 e-pairs = 128 diff columns)
#define BND  128   // diff columns per block
#define BK   16

#define FMA_ROW(r, a) \
    acc[r][0] = fmaf(a, bf.x, acc[r][0]); \
    acc[r][1] = fmaf(a, bf.y, acc[r][1]); \
    acc[r][2] = fmaf(a, bf.z, acc[r][2]); \
    acc[r][3] = fmaf(a, bf.w, acc[r][3]);

template <bool SQ>
__global__ __launch_bounds__(256) void k2_logits(
    const float* __restrict__ hbuf,
    const float* __restrict__ bw3, const float* __restrict__ bb3,
    const float* __restrict__ sw3, const float* __restrict__ sb3,
    const float* __restrict__ gum,
    const int* __restrict__ meta, const int* __restrict__ borig,
    unsigned char* __restrict__ bits) {
    __shared__ float hs[BK][BM + 4];    // transposed h tile, stride 68
    __shared__ float wt[BK][BND + 4];   // w-DIFF tile, stride 132
    int tid = threadIdx.x;
    int by = blockIdx.x;                // row-tile 0..8 (fast index -> L2 reuse of w3)
    int bx = blockIdx.y;                // e-tile   0..254 (128 e-pairs each)
    int r0 = by * BM;
    int cb = bx * BNW;                  // global w3 column base (= 2*e0)
    int S = meta[0];
    bool big = (r0 < S);                // row tiles are expert-uniform (64-aligned split)
    const float* w3 = big ? bw3 : sw3;
    const float* b3 = big ? bb3 : sb3;

    int lm  = tid >> 2;                 // h-load: row 0..63
    int lq  = tid & 3;                  // h-load: k quad
    int wk  = tid >> 4;                 // w-load: k row 0..15
    int wc  = (tid & 15) * 16;          // w-load: w3 col offset (16 cols -> 8 diffs)
    int wd  = (tid & 15) * 8;           // w-store: diff col offset

    int tm = tid >> 5;                  // 0..7 : 8 rows each
    int tn = tid & 31;                  // 0..31: 4 diff cols each

    float acc[8][4];
    #pragma unroll
    for (int i = 0; i < 8; ++i)
        #pragma unroll
        for (int j = 0; j < 4; ++j) acc[i][j] = 0.f;

    // prefetch tile 0 into registers
    const float* hrow = &hbuf[(size_t)(r0 + lm) * D3 + lq * 4];
    float4 hv = *(const float4*)hrow;
    const float* wrow = &w3[(size_t)wk * OUTCOLS + cb + wc];
    float4 wv0 = *(const float4*)&wrow[0];
    float4 wv1 = *(const float4*)&wrow[4];
    float4 wv2 = *(const float4*)&wrow[8];
    float4 wv3 = *(const float4*)&wrow[12];

    for (int k0 = 0;;) {
        __syncthreads();                // previous iter's LDS reads done
        hs[lq * 4 + 0][lm] = hv.x;
        hs[lq * 4 + 1][lm] = hv.y;
        hs[lq * 4 + 2][lm] = hv.z;
        hs[lq * 4 + 3][lm] = hv.w;
        {
            float4 d0, d1;
            d0.x = wv0.x - wv0.y;  d0.y = wv0.z - wv0.w;
            d0.z = wv1.x - wv1.y;  d0.w = wv1.z - wv1.w;
            d1.x = wv2.x - wv2.y;  d1.y = wv2.z - wv2.w;
            d1.z = wv3.x - wv3.y;  d1.w = wv3.z - wv3.w;
            *(float4*)&wt[wk][wd]     = d0;
            *(float4*)&wt[wk][wd + 4] = d1;
        }
        __syncthreads();
        k0 += BK;
        bool more = (k0 < D3);
        if (more) {                     // issue next tile's loads BEFORE compute
            hv = *(const float4*)&hrow[k0];
            const float* wr = &wrow[(size_t)k0 * OUTCOLS];
            wv0 = *(const float4*)&wr[0];
            wv1 = *(const float4*)&wr[4];
            wv2 = *(const float4*)&wr[8];
            wv3 = *(const float4*)&wr[12];
        }
        #pragma unroll
        for (int kk = 0; kk < BK; ++kk) {
            float4 a0 = *(const float4*)&hs[kk][tm * 8];
            float4 a1 = *(const float4*)&hs[kk][tm * 8 + 4];
            float4 bf = *(const float4*)&wt[kk][tn * 4];
            FMA_ROW(0, a0.x)
            FMA_ROW(1, a0.y)
            FMA_ROW(2, a0.z)
            FMA_ROW(3, a0.w)
            FMA_ROW(4, a1.x)
            FMA_ROW(5, a1.y)
            FMA_ROW(6, a1.z)
            FMA_ROW(7, a1.w)
        }
        if (!more) break;
    }

    // epilogue: bias-diff + gumbel-diff, compare, store bit bytes
    float4 bv0 = *(const float4*)&b3[cb + tn * 8];
    float4 bv1 = *(const float4*)&b3[cb + tn * 8 + 4];
    float bd0 = bv0.x - bv0.y;
    float bd1 = bv0.z - bv0.w;
    float bd2 = bv1.x - bv1.y;
    float bd3 = bv1.z - bv1.w;
    int ebase = bx * BND + tn * 4;      // first e-pair of this thread's 4

    int i0 = 0, j0 = 0;
    if (SQ) {
        // exact closed-form e -> (i,j): fe=(255.5-i)^2 at row starts is exactly
        // representable and sqrtf is correctly rounded -> exact; fixups for safety.
        float fe = 65280.25f - 2.0f * (float)ebase;
        i0 = (int)(255.5f - sqrtf(fe));
        if (i0 * (511 - i0) / 2 > ebase) --i0;
        if ((i0 + 1) * (510 - i0) / 2 <= ebase) ++i0;
        j0 = ebase - i0 * (511 - i0) / 2 + i0 + 1;
    }

    #pragma unroll
    for (int i = 0; i < 8; ++i) {
        int slot = r0 + tm * 8 + i;
        int b = borig[slot];
        if (b < 0) continue;            // pad slot
        const float* gp = &gum[(size_t)b * OUTCOLS + (size_t)ebase * 2];
        float4 gv0 = *(const float4*)&gp[0];
        float4 gv1 = *(const float4*)&gp[4];
        unsigned char c0 = ((acc[i][0] + bd0) + (gv0.x - gv0.y) >= 0.f) ? 1 : 0;
        unsigned char c1 = ((acc[i][1] + bd1) + (gv0.z - gv0.w) >= 0.f) ? 1 : 0;
        unsigned char c2 = ((acc[i][2] + bd2) + (gv1.x - gv1.y) >= 0.f) ? 1 : 0;
        unsigned char c3 = ((acc[i][3] + bd3) + (gv1.z - gv1.w) >= 0.f) ? 1 : 0;
        if (SQ) {
            size_t rowb = ((size_t)b << 16);
            int ii = i0, jj = j0;
            bits[rowb + ((size_t)ii << 8) + jj] = c0;
            if (++jj == 256) { ++ii; jj = ii + 1; }
            bits[rowb + ((size_t)ii << 8) + jj] = c1;
            if (++jj == 256) { ++ii; jj = ii + 1; }
            bits[rowb + ((size_t)ii << 8) + jj] = c2;
            if (++jj == 256) { ++ii; jj = ii + 1; }
            bits[rowb + ((size_t)ii << 8) + jj] = c3;
        } else {
            uchar4 v;
            v.x = c0; v.y = c1; v.z = c2; v.w = c3;
            *(uchar4*)&bits[(size_t)b * E_PAIRS + ebase] = v;
        }
    }
}

// ---------------- kernel 3 (square layout): aligned uint4 staging ------------
__global__ __launch_bounds__(256) void k3_expand_sq(
    const unsigned char* __restrict__ bits, float* __restrict__ out) {
    __shared__ unsigned char L[64][68];   // stride 68 bytes (17 dwords -> bank spread)
    const int ti_tab[10] = {0,0,0,0,1,1,1,2,2,3};
    const int tj_tab[10] = {0,1,2,3,1,2,3,2,3,3};
    int p = blockIdx.x;                   // 0..9
    int b = blockIdx.y;                   // 0..511
    int ti = ti_tab[p], tj = tj_tab[p];
    int t = threadIdx.x;

    // ---- stage bits: one aligned uint4 per thread (square rows are 256B) ----
    {
        int r = t >> 2;                   // 0..63
        int q = t & 3;                    // 0..3
        int i = ti * 64 + r;
        const unsigned char* src = &bits[(((size_t)b << 8) + i) * 256 + tj * 64 + q * 16];
        uint4 v = *(const uint4*)src;     // 16B aligned
        *(unsigned int*)&L[r][q * 16 + 0]  = v.x;   // stride 68 -> dword stores
        *(unsigned int*)&L[r][q * 16 + 4]  = v.y;
        *(unsigned int*)&L[r][q * 16 + 8]  = v.z;
        *(unsigned int*)&L[r][q * 16 + 12] = v.w;
    }
    __syncthreads();

    int h  = t >> 4;                      // 0..15  (row within group of 16)
    int w4 = (t & 15) * 4;                // col base, float4 granularity

    // ---- direct tile: out[b][ti*64+ii][tj*64 + w4 .. +3] ----
    {
        #pragma unroll
        for (int rr = 0; rr < 4; ++rr) {
            int ii = rr * 16 + h;
            int i_ = ti * 64 + ii;
            float4 v;
            if (ti == tj) {               // lower/diag cells of L are garbage; guarded
                int jj;
                jj = w4 + 0; v.x = (jj > ii) ? (float)L[ii][jj] : (jj < ii ? (float)L[jj][ii] : 0.f);
                jj = w4 + 1; v.y = (jj > ii) ? (float)L[ii][jj] : (jj < ii ? (float)L[jj][ii] : 0.f);
                jj = w4 + 2; v.z = (jj > ii) ? (float)L[ii][jj] : (jj < ii ? (float)L[jj][ii] : 0.f);
                jj = w4 + 3; v.w = (jj > ii) ? (float)L[ii][jj] : (jj < ii ? (float)L[jj][ii] : 0.f);
            } else {
                v.x = (float)L[ii][w4 + 0];
                v.y = (float)L[ii][w4 + 1];
                v.z = (float)L[ii][w4 + 2];
                v.w = (float)L[ii][w4 + 3];
            }
            size_t o = (((size_t)b * 256 + i_) * 256) + tj * 64 + w4;
            *(float4*)&out[o] = v;
        }
    }

    // ---- mirrored tile (off-diagonal only): out[b][tj*64+jj][ti*64 + w4 ..] ----
    if (ti != tj) {
        #pragma unroll
        for (int rr = 0; rr < 4; ++rr) {
            int jj = rr * 16 + h;
            int j_ = tj * 64 + jj;
            float4 v;                      // value(i=col, j=row) = L[col_local][jj]
            v.x = (float)L[w4 + 0][jj];
            v.y = (float)L[w4 + 1][jj];
            v.z = (float)L[w4 + 2][jj];
            v.w = (float)L[w4 + 3][jj];
            size_t o = (((size_t)b * 256 + j_) * 256) + ti * 64 + w4;
            *(float4*)&out[o] = v;
        }
    }
}

// ---------------- kernel 3 (packed fallback): original byte staging ----------
__global__ __launch_bounds__(256) void k3_expand(
    const unsigned char* __restrict__ bits, float* __restrict__ out) {
    __shared__ unsigned char L[64][68];
    const int ti_tab[10] = {0,0,0,0,1,1,1,2,2,3};
    const int tj_tab[10] = {0,1,2,3,1,2,3,2,3,3};
    int p = blockIdx.x;
    int b = blockIdx.y;
    int ti = ti_tab[p], tj = tj_tab[p];
    int t = threadIdx.x;
    {
        int r = t >> 2;
        int q = t & 3;
        int i = ti * 64 + r;
        long base = (long)b * E_PAIRS + (long)i * (511 - i) / 2 - i - 1;
        int j0 = tj * 64 + q * 16;
        #pragma unroll
        for (int k = 0; k < 16; ++k) {
            int j = j0 + k;
            unsigned char v = (j > i) ? bits[base + j] : (unsigned char)0;
            L[r][q * 16 + k] = v;
        }
    }
    __syncthreads();

    int h  = t >> 4;
    int w4 = (t & 15) * 4;
    {
        #pragma unroll
        for (int rr = 0; rr < 4; ++rr) {
            int ii = rr * 16 + h;
            int i_ = ti * 64 + ii;
            float4 v;
            if (ti == tj) {
                int jj;
                jj = w4 + 0; v.x = (jj > ii) ? (float)L[ii][jj] : (jj < ii ? (float)L[jj][ii] : 0.f);
                jj = w4 + 1; v.y = (jj > ii) ? (float)L[ii][jj] : (jj < ii ? (float)L[jj][ii] : 0.f);
                jj = w4 + 2; v.z = (jj > ii) ? (float)L[ii][jj] : (jj < ii ? (float)L[jj][ii] : 0.f);
                jj = w4 + 3; v.w = (jj > ii) ? (float)L[ii][jj] : (jj < ii ? (float)L[jj][ii] : 0.f);
            } else {
                v.x = (float)L[ii][w4 + 0];
                v.y = (float)L[ii][w4 + 1];
                v.z = (float)L[ii][w4 + 2];
                v.w = (float)L[ii][w4 + 3];
            }
            size_t o = (((size_t)b * 256 + i_) * 256) + tj * 64 + w4;
            *(float4*)&out[o] = v;
        }
    }
    if (ti != tj) {
        #pragma unroll
        for (int rr = 0; rr < 4; ++rr) {
            int jj = rr * 16 + h;
            int j_ = tj * 64 + jj;
            float4 v;
            v.x = (float)L[w4 + 0][jj];
            v.y = (float)L[w4 + 1][jj];
            v.z = (float)L[w4 + 2][jj];
            v.w = (float)L[w4 + 3][jj];
            size_t o = (((size_t)b * 256 + j_) * 256) + ti * 64 + w4;
            *(float4*)&out[o] = v;
        }
    }
}

// -----------------------------------------------------------------------------
extern "C" void kernel_launch(void* const* d_in, const int* in_sizes, int n_in,
                              void* d_out, int out_size, void* d_ws, size_t ws_size,
                              hipStream_t stream) {
    const float* x   = (const float*)d_in[0];
    const float* gum = (const float*)d_in[1];
    const float* bw0 = (const float*)d_in[2];  const float* bb0 = (const float*)d_in[3];
    const float* sw0 = (const float*)d_in[4];  const float* sb0 = (const float*)d_in[5];
    const float* bw1 = (const float*)d_in[6];  const float* bb1 = (const float*)d_in[7];
    const float* sw1 = (const float*)d_in[8];  const float* sb1 = (const float*)d_in[9];
    const float* bw2 = (const float*)d_in[10]; const float* bb2 = (const float*)d_in[11];
    const float* sw2 = (const float*)d_in[12]; const float* sb2 = (const float*)d_in[13];
    const float* bw3 = (const float*)d_in[14]; const float* bb3 = (const float*)d_in[15];
    const float* sw3 = (const float*)d_in[16]; const float* sb3 = (const float*)d_in[17];

    char* ws = (char*)d_ws;
    int*   meta  = (int*)ws;                           // 64 B
    int*   borig = (int*)(ws + 64);                    // 576 ints
    float* hbuf  = (float*)(ws + 4096);                // 576*1024 fp32 = 2.25 MB
    unsigned char* bits = (unsigned char*)(ws + 4096 + (size_t)SLOTS * D3 * 4);
    float* out = (float*)d_out;

    // square layout (aligned k3 staging) needs 4K + 2.25M + 33.55M ~= 35.9 MB
    size_t need_sq = 4096 + (size_t)SLOTS * D3 * 4 + (size_t)BATCH * 65536;
    bool sq = (ws_size >= need_sq);

    k0_sort<<<1, SLOTS, 0, stream>>>(x, meta, borig);
    k1_mlp<<<SLOTS, 256, 0, stream>>>(x, bw0, bb0, sw0, sb0, bw1, bb1, sw1, sb1,
                                      bw2, bb2, sw2, sb2, borig, hbuf);
    if (sq) {
        k2_logits<true><<<dim3(9, 255), 256, 0, stream>>>(hbuf, bw3, bb3, sw3, sb3,
                                                          gum, meta, borig, bits);
        k3_expand_sq<<<dim3(10, BATCH), 256, 0, stream>>>(bits, out);
    } else {
        k2_logits<false><<<dim3(9, 255), 256, 0, stream>>>(hbuf, bw3, bb3, sw3, sb3,
                                                           gum, meta, borig, bits);
        k3_expand<<<dim3(10, BATCH), 256, 0, stream>>>(bits, out);
    }
}

// Round 3
// 1077.777 us; speedup vs baseline: 1.0539x; 1.0539x over previous
//
#include <hip/hip_runtime.h>

#define N_NODES 256
#define COND    64
#define E_PAIRS 32640
#define OUTCOLS 65280
#define BATCH   512
#define SLOTS   576    // 9 row-tiles of 64 (big rows padded to 64, then small, then pad)
#define D1      256
#define D2      512
#define D3      1024

// ---------------- kernel 0: ballot-based stable sort into 64-aligned slots ---
__global__ void k0_sort(const float* __restrict__ x, int* __restrict__ meta,
                        int* __restrict__ borig) {
    __shared__ int wc[9];
    int t = threadIdx.x;                 // blockDim = 576 (9 waves)
    if (t < SLOTS) borig[t] = -1;        // pad default
    int m = 0;
    if (t < BATCH) m = (x[t * COND] > 0.0f) ? 1 : 0;
    unsigned long long bm = __ballot(m);
    int wave = t >> 6;
    int lane = t & 63;
    int lanePre = __popcll(bm & ((1ull << lane) - 1ull));
    if (lane == 0) wc[wave] = __popcll(bm);
    __syncthreads();
    int nbig = 0, preBig = 0;
    #pragma unroll
    for (int w = 0; w < 8; ++w) {        // waves 0..7 cover t<512
        int c = wc[w];
        if (w < wave) preBig += c;
        nbig += c;
    }
    int S = (nbig + 63) & ~63;           // big slots [0,S), small [S, S+nsmall)
    if (t < BATCH) {
        int onesBefore = preBig + lanePre;
        int slot = m ? onesBefore : (S + (t - onesBefore));
        borig[slot] = t;
    }
    if (t == 0) meta[0] = S;
}

// ---------------- kernel 1: MLP layers as tiled GEMMs (weights loaded once) --
// Old per-row k1 streamed the FULL weight set per block (576 x 2.6 MB ~ 1.5 GB
// of L2/L3 traffic). Tiled GEMM loads each 64-col weight panel once per row
// tile: ~25 MB total. 64x64 tile, 256 threads, 4x4 per thread, ReLU fused.
// GATHER=true (layer 0): rows indexed via borig into x; pad rows -> zeros.
template <bool GATHER, int K, int DOUT>
__global__ __launch_bounds__(256) void k1_gemm(
    const float* __restrict__ in,
    const float* __restrict__ wbig, const float* __restrict__ bbig,
    const float* __restrict__ wsml, const float* __restrict__ bsml,
    const int* __restrict__ meta, const int* __restrict__ borig,
    float* __restrict__ out) {
    __shared__ float hs[16][64 + 4];     // transposed act tile
    __shared__ float wt[16][64 + 4];     // weight tile
    int tid = threadIdx.x;
    int by = blockIdx.x;                 // row tile 0..8
    int bx = blockIdx.y;                 // col tile
    int r0 = by * 64;
    int cb = bx * 64;
    int S = meta[0];
    bool big = (r0 < S);                 // row tiles are expert-uniform
    const float* w = big ? wbig : wsml;
    const float* bias = big ? bbig : bsml;

    int lm = tid >> 2;                   // act-load row 0..63
    int lq = tid & 3;                    // act-load k quad
    int wk = tid >> 4;                   // w-load k row 0..15
    int wc = (tid & 15) * 4;             // w-load col offset

    int tm = tid >> 4;                   // 0..15 : rows tm*4..+3
    int tn = tid & 15;                   // 0..15 : cols tn*4..+3

    const float* hrow;
    if (GATHER) {
        int b = borig[r0 + lm];
        hrow = (b >= 0) ? &in[(size_t)b * K] : (const float*)0;
    } else {
        hrow = &in[(size_t)(r0 + lm) * K];   // pad rows hold garbage; harmless
    }

    float acc[4][4];
    #pragma unroll
    for (int i = 0; i < 4; ++i)
        #pragma unroll
        for (int j = 0; j < 4; ++j) acc[i][j] = 0.f;

    for (int k0 = 0; k0 < K; k0 += 16) {
        float4 hv = make_float4(0.f, 0.f, 0.f, 0.f);
        if (!GATHER || hrow) hv = *(const float4*)&hrow[k0 + lq * 4];
        float4 wv = *(const float4*)&w[(size_t)(k0 + wk) * DOUT + cb + wc];
        __syncthreads();
        hs[lq * 4 + 0][lm] = hv.x;
        hs[lq * 4 + 1][lm] = hv.y;
        hs[lq * 4 + 2][lm] = hv.z;
        hs[lq * 4 + 3][lm] = hv.w;
        *(float4*)&wt[wk][wc] = wv;
        __syncthreads();
        #pragma unroll
        for (int kk = 0; kk < 16; ++kk) {
            float4 a  = *(const float4*)&hs[kk][tm * 4];
            float4 bf = *(const float4*)&wt[kk][tn * 4];
            acc[0][0] = fmaf(a.x, bf.x, acc[0][0]);
            acc[0][1] = fmaf(a.x, bf.y, acc[0][1]);
            acc[0][2] = fmaf(a.x, bf.z, acc[0][2]);
            acc[0][3] = fmaf(a.x, bf.w, acc[0][3]);
            acc[1][0] = fmaf(a.y, bf.x, acc[1][0]);
            acc[1][1] = fmaf(a.y, bf.y, acc[1][1]);
            acc[1][2] = fmaf(a.y, bf.z, acc[1][2]);
            acc[1][3] = fmaf(a.y, bf.w, acc[1][3]);
            acc[2][0] = fmaf(a.z, bf.x, acc[2][0]);
            acc[2][1] = fmaf(a.z, bf.y, acc[2][1]);
            acc[2][2] = fmaf(a.z, bf.z, acc[2][2]);
            acc[2][3] = fmaf(a.z, bf.w, acc[2][3]);
            acc[3][0] = fmaf(a.w, bf.x, acc[3][0]);
            acc[3][1] = fmaf(a.w, bf.y, acc[3][1]);
            acc[3][2] = fmaf(a.w, bf.z, acc[3][2]);
            acc[3][3] = fmaf(a.w, bf.w, acc[3][3]);
        }
    }

    float4 bv = *(const float4*)&bias[cb + tn * 4];
    #pragma unroll
    for (int i = 0; i < 4; ++i) {
        float4 o;
        o.x = fmaxf(acc[i][0] + bv.x, 0.f);
        o.y = fmaxf(acc[i][1] + bv.y, 0.f);
        o.z = fmaxf(acc[i][2] + bv.z, 0.f);
        o.w = fmaxf(acc[i][3] + bv.w, 0.f);
        *(float4*)&out[(size_t)(r0 + tm * 4 + i) * DOUT + cb + tn * 4] = o;
    }
}

// ---------------- kernel 2: fp32 DIFFERENCE-GEMM (slots x 32640 e-pairs) ------
// g0>=g1  <=>  h.(w3[:,2e]-w3[:,2e+1]) + (b3d) + (gum0-gum1) >= 0.
// Round-1 proven form: VGPR 36, occupancy ~59%, 486 us. (Register-prefetch
// variant regressed: VGPR 56 -> occupancy 38% -> +25 us. Do not re-add.)
#define BM   64
#define BNW  256   // w3 columns per block (= 128 e-pairs = 128 diff columns)
#define BND  128   // diff columns per block
#define BK   16
__global__ __launch_bounds__(256) void k2_logits(
    const float* __restrict__ hbuf,
    const float* __restrict__ bw3, const float* __restrict__ bb3,
    const float* __restrict__ sw3, const float* __restrict__ sb3,
    const float* __restrict__ gum,
    const int* __restrict__ meta, const int* __restrict__ borig,
    unsigned char* __restrict__ bits) {
    __shared__ float hs[BK][BM + 4];    // transposed h tile, stride 68
    __shared__ float wt[BK][BND + 4];   // w-DIFF tile, stride 132
    int tid = threadIdx.x;
    int by = blockIdx.x;                // row-tile 0..8 (fast index -> L2 reuse of w3)
    int bx = blockIdx.y;                // e-tile   0..254 (128 e-pairs each)
    int r0 = by * BM;
    int cb = bx * BNW;                  // global w3 column base (= 2*e0)
    int S = meta[0];
    bool big = (r0 < S);                // row tiles are expert-uniform (64-aligned split)
    const float* w3 = big ? bw3 : sw3;
    const float* b3 = big ? bb3 : sb3;

    int lm  = tid >> 2;                 // h-load: row 0..63
    int lq  = tid & 3;                  // h-load: k quad
    int wk  = tid >> 4;                 // w-load: k row 0..15
    int wc  = (tid & 15) * 16;          // w-load: w3 col offset (16 cols -> 8 diffs)
    int wd  = (tid & 15) * 8;           // w-store: diff col offset

    int tm = tid >> 5;                  // 0..7 : 8 rows each
    int tn = tid & 31;                  // 0..31: 4 diff cols each

    float acc[8][4];
    #pragma unroll
    for (int i = 0; i < 8; ++i)
        #pragma unroll
        for (int j = 0; j < 4; ++j) acc[i][j] = 0.f;

    for (int k0 = 0; k0 < D3; k0 += BK) {
        float4 hv = *(const float4*)&hbuf[(size_t)(r0 + lm) * D3 + k0 + lq * 4];
        const float* wrow = &w3[(size_t)(k0 + wk) * OUTCOLS + cb + wc];
        float4 wv0 = *(const float4*)&wrow[0];
        float4 wv1 = *(const float4*)&wrow[4];
        float4 wv2 = *(const float4*)&wrow[8];
        float4 wv3 = *(const float4*)&wrow[12];
        __syncthreads();                // previous iter's reads done before overwrite
        hs[lq * 4 + 0][lm] = hv.x;
        hs[lq * 4 + 1][lm] = hv.y;
        hs[lq * 4 + 2][lm] = hv.z;
        hs[lq * 4 + 3][lm] = hv.w;
        float4 d0, d1;
        d0.x = wv0.x - wv0.y;  d0.y = wv0.z - wv0.w;
        d0.z = wv1.x - wv1.y;  d0.w = wv1.z - wv1.w;
        d1.x = wv2.x - wv2.y;  d1.y = wv2.z - wv2.w;
        d1.z = wv3.x - wv3.y;  d1.w = wv3.z - wv3.w;
        *(float4*)&wt[wk][wd]     = d0;
        *(float4*)&wt[wk][wd + 4] = d1;
        __syncthreads();
        #pragma unroll
        for (int kk = 0; kk < BK; ++kk) {
            float4 a0 = *(const float4*)&hs[kk][tm * 8];
            float4 a1 = *(const float4*)&hs[kk][tm * 8 + 4];
            float4 bf = *(const float4*)&wt[kk][tn * 4];
            float am[8] = {a0.x, a0.y, a0.z, a0.w, a1.x, a1.y, a1.z, a1.w};
            float bn[4] = {bf.x, bf.y, bf.z, bf.w};
            #pragma unroll
            for (int i = 0; i < 8; ++i)
                #pragma unroll
                for (int j = 0; j < 4; ++j)
                    acc[i][j] = fmaf(am[i], bn[j], acc[i][j]);
        }
    }

    // epilogue: bias-diff + gumbel-diff, compare, store bit bytes
    float4 bv0 = *(const float4*)&b3[cb + tn * 8];
    float4 bv1 = *(const float4*)&b3[cb + tn * 8 + 4];
    float bd0 = bv0.x - bv0.y;
    float bd1 = bv0.z - bv0.w;
    float bd2 = bv1.x - bv1.y;
    float bd3 = bv1.z - bv1.w;
    int ebase = bx * BND + tn * 4;      // first e-pair of this thread's 4
    #pragma unroll
    for (int i = 0; i < 8; ++i) {
        int slot = r0 + tm * 8 + i;
        int b = borig[slot];
        if (b < 0) continue;            // pad slot
        const float* gp = &gum[(size_t)b * OUTCOLS + (size_t)ebase * 2];
        float4 gv0 = *(const float4*)&gp[0];
        float4 gv1 = *(const float4*)&gp[4];
        uchar4 v;
        v.x = ((acc[i][0] + bd0) + (gv0.x - gv0.y) >= 0.f) ? 1 : 0;
        v.y = ((acc[i][1] + bd1) + (gv0.z - gv0.w) >= 0.f) ? 1 : 0;
        v.z = ((acc[i][2] + bd2) + (gv1.x - gv1.y) >= 0.f) ? 1 : 0;
        v.w = ((acc[i][3] + bd3) + (gv1.z - gv1.w) >= 0.f) ? 1 : 0;
        *(uchar4*)&bits[(size_t)b * E_PAIRS + ebase] = v;
    }
}

// ---------------- kernel 3: tiled bit->fp32 expansion with LDS transpose ------
__global__ __launch_bounds__(256) void k3_expand(
    const unsigned char* __restrict__ bits, float* __restrict__ out) {
    __shared__ unsigned char L[64][68];   // stride 68 bytes
    const int ti_tab[10] = {0,0,0,0,1,1,1,2,2,3};
    const int tj_tab[10] = {0,1,2,3,1,2,3,2,3,3};
    int p = blockIdx.x;                   // 0..9
    int b = blockIdx.y;                   // 0..511
    int ti = ti_tab[p], tj = tj_tab[p];
    int t = threadIdx.x;

    // ---- stage bits: row r (i = ti*64+r), 16 bytes per thread ----
    {
        int r = t >> 2;                   // 0..63
        int q = t & 3;                    // 0..3
        int i = ti * 64 + r;
        // e(i,j) = i*(511-i)/2 + j - i - 1  (valid for j > i)
        long base = (long)b * E_PAIRS + (long)i * (511 - i) / 2 - i - 1;
        int j0 = tj * 64 + q * 16;
        #pragma unroll
        for (int k = 0; k < 16; ++k) {
            int j = j0 + k;
            unsigned char v = (j > i) ? bits[base + j] : (unsigned char)0;
            L[r][q * 16 + k] = v;
        }
    }
    __syncthreads();

    int h  = t >> 4;                      // 0..15  (row within group of 16)
    int w4 = (t & 15) * 4;                // col base, float4 granularity

    // ---- direct tile: out[b][ti*64+ii][tj*64 + w4 .. +3] ----
    {
        #pragma unroll
        for (int rr = 0; rr < 4; ++rr) {
            int ii = rr * 16 + h;
            int i_ = ti * 64 + ii;
            float4 v;
            if (ti == tj) {
                int jj;
                jj = w4 + 0; v.x = (jj > ii) ? (float)L[ii][jj] : (jj < ii ? (float)L[jj][ii] : 0.f);
                jj = w4 + 1; v.y = (jj > ii) ? (float)L[ii][jj] : (jj < ii ? (float)L[jj][ii] : 0.f);
                jj = w4 + 2; v.z = (jj > ii) ? (float)L[ii][jj] : (jj < ii ? (float)L[jj][ii] : 0.f);
                jj = w4 + 3; v.w = (jj > ii) ? (float)L[ii][jj] : (jj < ii ? (float)L[jj][ii] : 0.f);
            } else {
                v.x = (float)L[ii][w4 + 0];
                v.y = (float)L[ii][w4 + 1];
                v.z = (float)L[ii][w4 + 2];
                v.w = (float)L[ii][w4 + 3];
            }
            size_t o = (((size_t)b * 256 + i_) * 256) + tj * 64 + w4;
            *(float4*)&out[o] = v;
        }
    }

    // ---- mirrored tile (off-diagonal only): out[b][tj*64+jj][ti*64 + w4 ..] ----
    if (ti != tj) {
        #pragma unroll
        for (int rr = 0; rr < 4; ++rr) {
            int jj = rr * 16 + h;
            int j_ = tj * 64 + jj;
            float4 v;                      // value(i=col, j=row) = L[col_local][jj]
            v.x = (float)L[w4 + 0][jj];
            v.y = (float)L[w4 + 1][jj];
            v.z = (float)L[w4 + 2][jj];
            v.w = (float)L[w4 + 3][jj];
            size_t o = (((size_t)b * 256 + j_) * 256) + ti * 64 + w4;
            *(float4*)&out[o] = v;
        }
    }
}

// -----------------------------------------------------------------------------
extern "C" void kernel_launch(void* const* d_in, const int* in_sizes, int n_in,
                              void* d_out, int out_size, void* d_ws, size_t ws_size,
                              hipStream_t stream) {
    const float* x   = (const float*)d_in[0];
    const float* gum = (const float*)d_in[1];
    const float* bw0 = (const float*)d_in[2];  const float* bb0 = (const float*)d_in[3];
    const float* sw0 = (const float*)d_in[4];  const float* sb0 = (const float*)d_in[5];
    const float* bw1 = (const float*)d_in[6];  const float* bb1 = (const float*)d_in[7];
    const float* sw1 = (const float*)d_in[8];  const float* sb1 = (const float*)d_in[9];
    const float* bw2 = (const float*)d_in[10]; const float* bb2 = (const float*)d_in[11];
    const float* sw2 = (const float*)d_in[12]; const float* sb2 = (const float*)d_in[13];
    const float* bw3 = (const float*)d_in[14]; const float* bb3 = (const float*)d_in[15];
    const float* sw3 = (const float*)d_in[16]; const float* sb3 = (const float*)d_in[17];

    char* ws = (char*)d_ws;
    int*   meta  = (int*)ws;                              // 64 B
    int*   borig = (int*)(ws + 64);                       // 576 ints
    float* act1  = (float*)(ws + 4096);                   // 576*256  = 576 KB
    float* act2  = (float*)(ws + 4096 + 589824);          // 576*512  = 1.125 MB
    float* hbuf  = (float*)(ws + 4096 + 589824 + 1179648);// 576*1024 = 2.25 MB
    unsigned char* bits = (unsigned char*)(ws + 4194304); // 512*32640 = 16.7 MB
    float* out = (float*)d_out;

    k0_sort<<<1, SLOTS, 0, stream>>>(x, meta, borig);
    k1_gemm<true,  COND, D1><<<dim3(9, D1 / 64), 256, 0, stream>>>(
        x,    bw0, bb0, sw0, sb0, meta, borig, act1);
    k1_gemm<false, D1,   D2><<<dim3(9, D2 / 64), 256, 0, stream>>>(
        act1, bw1, bb1, sw1, sb1, meta, borig, act2);
    k1_gemm<false, D2,   D3><<<dim3(9, D3 / 64), 256, 0, stream>>>(
        act2, bw2, bb2, sw2, sb2, meta, borig, hbuf);
    k2_logits<<<dim3(9, 255), 256, 0, stream>>>(hbuf, bw3, bb3, sw3, sb3, gum,
                                                meta, borig, bits);
    k3_expand<<<dim3(10, BATCH), 256, 0, stream>>>(bits, out);
}

// Round 4
// 1053.998 us; speedup vs baseline: 1.0777x; 1.0226x over previous
//
#include <hip/hip_runtime.h>

#define N_NODES 256
#define COND    64
#define E_PAIRS 32640
#define OUTCOLS 65280
#define BATCH   512
#define SLOTS   576    // 9 row-tiles of 64 (big rows padded to 64, then small, then pad)
#define D1      256
#define D2      512
#define D3      1024

// ---------------- kernel 0: ballot-based stable sort into 64-aligned slots ---
__global__ void k0_sort(const float* __restrict__ x, int* __restrict__ meta,
                        int* __restrict__ borig) {
    __shared__ int wc[9];
    int t = threadIdx.x;                 // blockDim = 576 (9 waves)
    if (t < SLOTS) borig[t] = -1;        // pad default
    int m = 0;
    if (t < BATCH) m = (x[t * COND] > 0.0f) ? 1 : 0;
    unsigned long long bm = __ballot(m);
    int wave = t >> 6;
    int lane = t & 63;
    int lanePre = __popcll(bm & ((1ull << lane) - 1ull));
    if (lane == 0) wc[wave] = __popcll(bm);
    __syncthreads();
    int nbig = 0, preBig = 0;
    #pragma unroll
    for (int w = 0; w < 8; ++w) {        // waves 0..7 cover t<512
        int c = wc[w];
        if (w < wave) preBig += c;
        nbig += c;
    }
    int S = (nbig + 63) & ~63;           // big slots [0,S), small [S, S+nsmall)
    if (t < BATCH) {
        int onesBefore = preBig + lanePre;
        int slot = m ? onesBefore : (S + (t - onesBefore));
        borig[slot] = t;
    }
    if (t == 0) meta[0] = S;
}

// ---------------- kernel 1: MLP layers as tiled GEMMs (weights loaded once) --
// 64x64 tile, 256 threads, 4x4 per thread, ReLU fused.
// GATHER=true (layer 0): rows indexed via borig into x; pad rows -> zeros.
template <bool GATHER, int K, int DOUT>
__global__ __launch_bounds__(256) void k1_gemm(
    const float* __restrict__ in,
    const float* __restrict__ wbig, const float* __restrict__ bbig,
    const float* __restrict__ wsml, const float* __restrict__ bsml,
    const int* __restrict__ meta, const int* __restrict__ borig,
    float* __restrict__ out) {
    __shared__ float hs[16][64 + 4];     // transposed act tile
    __shared__ float wt[16][64 + 4];     // weight tile
    int tid = threadIdx.x;
    int by = blockIdx.x;                 // row tile 0..8
    int bx = blockIdx.y;                 // col tile
    int r0 = by * 64;
    int cb = bx * 64;
    int S = meta[0];
    bool big = (r0 < S);                 // row tiles are expert-uniform
    const float* w = big ? wbig : wsml;
    const float* bias = big ? bbig : bsml;

    int lm = tid >> 2;                   // act-load row 0..63
    int lq = tid & 3;                    // act-load k quad
    int wk = tid >> 4;                   // w-load k row 0..15
    int wc = (tid & 15) * 4;             // w-load col offset

    int tm = tid >> 4;                   // 0..15 : rows tm*4..+3
    int tn = tid & 15;                   // 0..15 : cols tn*4..+3

    const float* hrow;
    if (GATHER) {
        int b = borig[r0 + lm];
        hrow = (b >= 0) ? &in[(size_t)b * K] : (const float*)0;
    } else {
        hrow = &in[(size_t)(r0 + lm) * K];   // pad rows hold garbage; harmless
    }

    float acc[4][4];
    #pragma unroll
    for (int i = 0; i < 4; ++i)
        #pragma unroll
        for (int j = 0; j < 4; ++j) acc[i][j] = 0.f;

    for (int k0 = 0; k0 < K; k0 += 16) {
        float4 hv = make_float4(0.f, 0.f, 0.f, 0.f);
        if (!GATHER || hrow) hv = *(const float4*)&hrow[k0 + lq * 4];
        float4 wv = *(const float4*)&w[(size_t)(k0 + wk) * DOUT + cb + wc];
        __syncthreads();
        hs[lq * 4 + 0][lm] = hv.x;
        hs[lq * 4 + 1][lm] = hv.y;
        hs[lq * 4 + 2][lm] = hv.z;
        hs[lq * 4 + 3][lm] = hv.w;
        *(float4*)&wt[wk][wc] = wv;
        __syncthreads();
        #pragma unroll
        for (int kk = 0; kk < 16; ++kk) {
            float4 a  = *(const float4*)&hs[kk][tm * 4];
            float4 bf = *(const float4*)&wt[kk][tn * 4];
            acc[0][0] = fmaf(a.x, bf.x, acc[0][0]);
            acc[0][1] = fmaf(a.x, bf.y, acc[0][1]);
            acc[0][2] = fmaf(a.x, bf.z, acc[0][2]);
            acc[0][3] = fmaf(a.x, bf.w, acc[0][3]);
            acc[1][0] = fmaf(a.y, bf.x, acc[1][0]);
            acc[1][1] = fmaf(a.y, bf.y, acc[1][1]);
            acc[1][2] = fmaf(a.y, bf.z, acc[1][2]);
            acc[1][3] = fmaf(a.y, bf.w, acc[1][3]);
            acc[2][0] = fmaf(a.z, bf.x, acc[2][0]);
            acc[2][1] = fmaf(a.z, bf.y, acc[2][1]);
            acc[2][2] = fmaf(a.z, bf.z, acc[2][2]);
            acc[2][3] = fmaf(a.z, bf.w, acc[2][3]);
            acc[3][0] = fmaf(a.w, bf.x, acc[3][0]);
            acc[3][1] = fmaf(a.w, bf.y, acc[3][1]);
            acc[3][2] = fmaf(a.w, bf.z, acc[3][2]);
            acc[3][3] = fmaf(a.w, bf.w, acc[3][3]);
        }
    }

    float4 bv = *(const float4*)&bias[cb + tn * 4];
    #pragma unroll
    for (int i = 0; i < 4; ++i) {
        float4 o;
        o.x = fmaxf(acc[i][0] + bv.x, 0.f);
        o.y = fmaxf(acc[i][1] + bv.y, 0.f);
        o.z = fmaxf(acc[i][2] + bv.z, 0.f);
        o.w = fmaxf(acc[i][3] + bv.w, 0.f);
        *(float4*)&out[(size_t)(r0 + tm * 4 + i) * DOUT + cb + tn * 4] = o;
    }
}

// ---------------- kernel 2: fp32 DIFFERENCE-GEMM (slots x 32640 e-pairs) ------
// g0>=g1  <=>  h.(w3[:,2e]-w3[:,2e+1]) + (b3d) + (gum0-gum1) >= 0.
// Inner loop = round-1 proven form (VGPR 36, occ ~58%; register-prefetch
// variant regressed to occ 38% — do not re-add).
// NEW: XCD-aware 1D grid. wgid = r + 8*(by + 9*q), bx = 8q+r. XCD r (= wgid%8
// round-robin) owns col-tiles {bx % 8 == r}; the 9 row-tiles of each col-tile
// run consecutively ON THE SAME XCD, phase-aligned in K -> each w3 panel is
// fetched from HBM once and shared via that XCD's L2 (was: 9 row-tiles spread
// across 8 XCDs -> 2x HBM over-fetch, FETCH 1.37 GB vs 690 MB unique).
#define BM   64
#define BNW  256   // w3 columns per block (= 128 e-pairs = 128 diff columns)
#define BND  128   // diff columns per block
#define BK   16
__global__ __launch_bounds__(256) void k2_logits(
    const float* __restrict__ hbuf,
    const float* __restrict__ bw3, const float* __restrict__ bb3,
    const float* __restrict__ sw3, const float* __restrict__ sb3,
    const float* __restrict__ gum,
    const int* __restrict__ meta, const int* __restrict__ borig,
    unsigned char* __restrict__ bits) {
    __shared__ float hs[BK][BM + 4];    // transposed h tile, stride 68
    __shared__ float wt[BK][BND + 4];   // w-DIFF tile, stride 132
    int tid = threadIdx.x;

    int wgid = blockIdx.x;              // 0..2303
    int r  = wgid & 7;                  // XCD slot
    int s_ = wgid >> 3;                 // 0..287
    int by = s_ % 9;                    // row tile 0..8
    int q  = s_ / 9;                    // col chunk 0..31
    int bx = q * 8 + r;                 // col tile 0..255
    if (bx >= 255) return;              // 9 idle blocks (pad to dense bijection)

    int r0 = by * BM;
    int cb = bx * BNW;                  // global w3 column base (= 2*e0)
    int S = meta[0];
    bool big = (r0 < S);                // row tiles are expert-uniform (64-aligned split)
    const float* w3 = big ? bw3 : sw3;
    const float* b3 = big ? bb3 : sb3;

    int lm  = tid >> 2;                 // h-load: row 0..63
    int lq  = tid & 3;                  // h-load: k quad
    int wk  = tid >> 4;                 // w-load: k row 0..15
    int wc  = (tid & 15) * 16;          // w-load: w3 col offset (16 cols -> 8 diffs)
    int wd  = (tid & 15) * 8;           // w-store: diff col offset

    int tm = tid >> 5;                  // 0..7 : 8 rows each
    int tn = tid & 31;                  // 0..31: 4 diff cols each

    float acc[8][4];
    #pragma unroll
    for (int i = 0; i < 8; ++i)
        #pragma unroll
        for (int j = 0; j < 4; ++j) acc[i][j] = 0.f;

    for (int k0 = 0; k0 < D3; k0 += BK) {
        float4 hv = *(const float4*)&hbuf[(size_t)(r0 + lm) * D3 + k0 + lq * 4];
        const float* wrow = &w3[(size_t)(k0 + wk) * OUTCOLS + cb + wc];
        float4 wv0 = *(const float4*)&wrow[0];
        float4 wv1 = *(const float4*)&wrow[4];
        float4 wv2 = *(const float4*)&wrow[8];
        float4 wv3 = *(const float4*)&wrow[12];
        __syncthreads();                // previous iter's reads done before overwrite
        hs[lq * 4 + 0][lm] = hv.x;
        hs[lq * 4 + 1][lm] = hv.y;
        hs[lq * 4 + 2][lm] = hv.z;
        hs[lq * 4 + 3][lm] = hv.w;
        float4 d0, d1;
        d0.x = wv0.x - wv0.y;  d0.y = wv0.z - wv0.w;
        d0.z = wv1.x - wv1.y;  d0.w = wv1.z - wv1.w;
        d1.x = wv2.x - wv2.y;  d1.y = wv2.z - wv2.w;
        d1.z = wv3.x - wv3.y;  d1.w = wv3.z - wv3.w;
        *(float4*)&wt[wk][wd]     = d0;
        *(float4*)&wt[wk][wd + 4] = d1;
        __syncthreads();
        #pragma unroll
        for (int kk = 0; kk < BK; ++kk) {
            float4 a0 = *(const float4*)&hs[kk][tm * 8];
            float4 a1 = *(const float4*)&hs[kk][tm * 8 + 4];
            float4 bf = *(const float4*)&wt[kk][tn * 4];
            float am[8] = {a0.x, a0.y, a0.z, a0.w, a1.x, a1.y, a1.z, a1.w};
            float bn[4] = {bf.x, bf.y, bf.z, bf.w};
            #pragma unroll
            for (int i = 0; i < 8; ++i)
                #pragma unroll
                for (int j = 0; j < 4; ++j)
                    acc[i][j] = fmaf(am[i], bn[j], acc[i][j]);
        }
    }

    // epilogue: bias-diff + gumbel-diff, compare, store bit bytes
    float4 bv0 = *(const float4*)&b3[cb + tn * 8];
    float4 bv1 = *(const float4*)&b3[cb + tn * 8 + 4];
    float bd0 = bv0.x - bv0.y;
    float bd1 = bv0.z - bv0.w;
    float bd2 = bv1.x - bv1.y;
    float bd3 = bv1.z - bv1.w;
    int ebase = bx * BND + tn * 4;      // first e-pair of this thread's 4
    #pragma unroll
    for (int i = 0; i < 8; ++i) {
        int slot = r0 + tm * 8 + i;
        int b = borig[slot];
        if (b < 0) continue;            // pad slot
        const float* gp = &gum[(size_t)b * OUTCOLS + (size_t)ebase * 2];
        float4 gv0 = *(const float4*)&gp[0];
        float4 gv1 = *(const float4*)&gp[4];
        uchar4 v;
        v.x = ((acc[i][0] + bd0) + (gv0.x - gv0.y) >= 0.f) ? 1 : 0;
        v.y = ((acc[i][1] + bd1) + (gv0.z - gv0.w) >= 0.f) ? 1 : 0;
        v.z = ((acc[i][2] + bd2) + (gv1.x - gv1.y) >= 0.f) ? 1 : 0;
        v.w = ((acc[i][3] + bd3) + (gv1.z - gv1.w) >= 0.f) ? 1 : 0;
        *(uchar4*)&bits[(size_t)b * E_PAIRS + ebase] = v;
    }
}

// ---------------- kernel 3: tiled bit->fp32 expansion with LDS transpose ------
__global__ __launch_bounds__(256) void k3_expand(
    const unsigned char* __restrict__ bits, float* __restrict__ out) {
    __shared__ unsigned char L[64][68];   // stride 68 bytes
    const int ti_tab[10] = {0,0,0,0,1,1,1,2,2,3};
    const int tj_tab[10] = {0,1,2,3,1,2,3,2,3,3};
    int p = blockIdx.x;                   // 0..9
    int b = blockIdx.y;                   // 0..511
    int ti = ti_tab[p], tj = tj_tab[p];
    int t = threadIdx.x;

    // ---- stage bits: row r (i = ti*64+r), 16 bytes per thread ----
    {
        int r = t >> 2;                   // 0..63
        int q = t & 3;                    // 0..3
        int i = ti * 64 + r;
        // e(i,j) = i*(511-i)/2 + j - i - 1  (valid for j > i)
        long base = (long)b * E_PAIRS + (long)i * (511 - i) / 2 - i - 1;
        int j0 = tj * 64 + q * 16;
        #pragma unroll
        for (int k = 0; k < 16; ++k) {
            int j = j0 + k;
            unsigned char v = (j > i) ? bits[base + j] : (unsigned char)0;
            L[r][q * 16 + k] = v;
        }
    }
    __syncthreads();

    int h  = t >> 4;                      // 0..15  (row within group of 16)
    int w4 = (t & 15) * 4;                // col base, float4 granularity

    // ---- direct tile: out[b][ti*64+ii][tj*64 + w4 .. +3] ----
    {
        #pragma unroll
        for (int rr = 0; rr < 4; ++rr) {
            int ii = rr * 16 + h;
            int i_ = ti * 64 + ii;
            float4 v;
            if (ti == tj) {
                int jj;
                jj = w4 + 0; v.x = (jj > ii) ? (float)L[ii][jj] : (jj < ii ? (float)L[jj][ii] : 0.f);
                jj = w4 + 1; v.y = (jj > ii) ? (float)L[ii][jj] : (jj < ii ? (float)L[jj][ii] : 0.f);
                jj = w4 + 2; v.z = (jj > ii) ? (float)L[ii][jj] : (jj < ii ? (float)L[jj][ii] : 0.f);
                jj = w4 + 3; v.w = (jj > ii) ? (float)L[ii][jj] : (jj < ii ? (float)L[jj][ii] : 0.f);
            } else {
                v.x = (float)L[ii][w4 + 0];
                v.y = (float)L[ii][w4 + 1];
                v.z = (float)L[ii][w4 + 2];
                v.w = (float)L[ii][w4 + 3];
            }
            size_t o = (((size_t)b * 256 + i_) * 256) + tj * 64 + w4;
            *(float4*)&out[o] = v;
        }
    }

    // ---- mirrored tile (off-diagonal only): out[b][tj*64+jj][ti*64 + w4 ..] ----
    if (ti != tj) {
        #pragma unroll
        for (int rr = 0; rr < 4; ++rr) {
            int jj = rr * 16 + h;
            int j_ = tj * 64 + jj;
            float4 v;                      // value(i=col, j=row) = L[col_local][jj]
            v.x = (float)L[w4 + 0][jj];
            v.y = (float)L[w4 + 1][jj];
            v.z = (float)L[w4 + 2][jj];
            v.w = (float)L[w4 + 3][jj];
            size_t o = (((size_t)b * 256 + j_) * 256) + ti * 64 + w4;
            *(float4*)&out[o] = v;
        }
    }
}

// -----------------------------------------------------------------------------
extern "C" void kernel_launch(void* const* d_in, const int* in_sizes, int n_in,
                              void* d_out, int out_size, void* d_ws, size_t ws_size,
                              hipStream_t stream) {
    const float* x   = (const float*)d_in[0];
    const float* gum = (const float*)d_in[1];
    const float* bw0 = (const float*)d_in[2];  const float* bb0 = (const float*)d_in[3];
    const float* sw0 = (const float*)d_in[4];  const float* sb0 = (const float*)d_in[5];
    const float* bw1 = (const float*)d_in[6];  const float* bb1 = (const float*)d_in[7];
    const float* sw1 = (const float*)d_in[8];  const float* sb1 = (const float*)d_in[9];
    const float* bw2 = (const float*)d_in[10]; const float* bb2 = (const float*)d_in[11];
    const float* sw2 = (const float*)d_in[12]; const float* sb2 = (const float*)d_in[13];
    const float* bw3 = (const float*)d_in[14]; const float* bb3 = (const float*)d_in[15];
    const float* sw3 = (const float*)d_in[16]; const float* sb3 = (const float*)d_in[17];

    char* ws = (char*)d_ws;
    int*   meta  = (int*)ws;                              // 64 B
    int*   borig = (int*)(ws + 64);                       // 576 ints
    float* act1  = (float*)(ws + 4096);                   // 576*256  = 576 KB
    float* act2  = (float*)(ws + 4096 + 589824);          // 576*512  = 1.125 MB
    float* hbuf  = (float*)(ws + 4096 + 589824 + 1179648);// 576*1024 = 2.25 MB
    unsigned char* bits = (unsigned char*)(ws + 4194304); // 512*32640 = 16.7 MB
    float* out = (float*)d_out;

    k0_sort<<<1, SLOTS, 0, stream>>>(x, meta, borig);
    k1_gemm<true,  COND, D1><<<dim3(9, D1 / 64), 256, 0, stream>>>(
        x,    bw0, bb0, sw0, sb0, meta, borig, act1);
    k1_gemm<false, D1,   D2><<<dim3(9, D2 / 64), 256, 0, stream>>>(
        act1, bw1, bb1, sw1, sb1, meta, borig, act2);
    k1_gemm<false, D2,   D3><<<dim3(9, D3 / 64), 256, 0, stream>>>(
        act2, bw2, bb2, sw2, sb2, meta, borig, hbuf);
    k2_logits<<<2304, 256, 0, stream>>>(hbuf, bw3, bb3, sw3, sb3, gum,
                                        meta, borig, bits);
    k3_expand<<<dim3(10, BATCH), 256, 0, stream>>>(bits, out);
}

// Round 5
// 1050.265 us; speedup vs baseline: 1.0815x; 1.0036x over previous
//
#include <hip/hip_runtime.h>

#define N_NODES 256
#define COND    64
#define E_PAIRS 32640
#define OUTCOLS 65280
#define BATCH   512
#define SLOTS   576    // 9 row-tiles of 64 (big rows padded to 64, then small, then pad)
#define D1      256
#define D2      512
#define D3      1024

typedef __attribute__((ext_vector_type(8))) short bf16x8;   // 8 bf16 = 4 VGPR (MFMA A/B frag)
typedef __attribute__((ext_vector_type(4))) float f32x4;    // MFMA C/D frag

static __device__ __forceinline__ unsigned short f2bf(float f) {   // RNE float->bf16
    unsigned int u = __float_as_uint(f);
    u += 0x7FFF + ((u >> 16) & 1);
    return (unsigned short)(u >> 16);
}
static __device__ __forceinline__ float bf2f(unsigned short h) {
    return __uint_as_float(((unsigned int)h) << 16);
}

// ---------------- kernel 0: ballot-based stable sort into 64-aligned slots ---
__global__ void k0_sort(const float* __restrict__ x, int* __restrict__ meta,
                        int* __restrict__ borig) {
    __shared__ int wc[9];
    int t = threadIdx.x;                 // blockDim = 576 (9 waves)
    if (t < SLOTS) borig[t] = -1;        // pad default
    int m = 0;
    if (t < BATCH) m = (x[t * COND] > 0.0f) ? 1 : 0;
    unsigned long long bm = __ballot(m);
    int wave = t >> 6;
    int lane = t & 63;
    int lanePre = __popcll(bm & ((1ull << lane) - 1ull));
    if (lane == 0) wc[wave] = __popcll(bm);
    __syncthreads();
    int nbig = 0, preBig = 0;
    #pragma unroll
    for (int w = 0; w < 8; ++w) {        // waves 0..7 cover t<512
        int c = wc[w];
        if (w < wave) preBig += c;
        nbig += c;
    }
    int S = (nbig + 63) & ~63;           // big slots [0,S), small [S, S+nsmall)
    if (t < BATCH) {
        int onesBefore = preBig + lanePre;
        int slot = m ? onesBefore : (S + (t - onesBefore));
        borig[slot] = t;
    }
    if (t == 0) meta[0] = S;
}

// ---------------- kernel 1: MLP layers as tiled GEMMs ------------------------
// 64x64 tile, 256 threads, 4x4 per thread, ReLU fused.
// GATHER (layer 0): rows via borig. SPLIT (layer 2): write h as 3 bf16 limbs
// (h = h0+h1+h2, residual <= 2^-27 |h|) for the MFMA logits kernel.
template <bool GATHER, int K, int DOUT, bool SPLIT>
__global__ __launch_bounds__(256) void k1_gemm(
    const float* __restrict__ in,
    const float* __restrict__ wbig, const float* __restrict__ bbig,
    const float* __restrict__ wsml, const float* __restrict__ bsml,
    const int* __restrict__ meta, const int* __restrict__ borig,
    float* __restrict__ out,
    unsigned short* __restrict__ hb0, unsigned short* __restrict__ hb1,
    unsigned short* __restrict__ hb2) {
    __shared__ float hs[16][64 + 4];     // transposed act tile
    __shared__ float wt[16][64 + 4];     // weight tile
    int tid = threadIdx.x;
    int by = blockIdx.x;                 // row tile 0..8
    int bx = blockIdx.y;                 // col tile
    int r0 = by * 64;
    int cb = bx * 64;
    int S = meta[0];
    bool big = (r0 < S);                 // row tiles are expert-uniform
    const float* w = big ? wbig : wsml;
    const float* bias = big ? bbig : bsml;

    int lm = tid >> 2;                   // act-load row 0..63
    int lq = tid & 3;                    // act-load k quad
    int wk = tid >> 4;                   // w-load k row 0..15
    int wc = (tid & 15) * 4;             // w-load col offset

    int tm = tid >> 4;                   // 0..15 : rows tm*4..+3
    int tn = tid & 15;                   // 0..15 : cols tn*4..+3

    const float* hrow;
    if (GATHER) {
        int b = borig[r0 + lm];
        hrow = (b >= 0) ? &in[(size_t)b * K] : (const float*)0;
    } else {
        hrow = &in[(size_t)(r0 + lm) * K];   // pad rows hold garbage; harmless
    }

    float acc[4][4];
    #pragma unroll
    for (int i = 0; i < 4; ++i)
        #pragma unroll
        for (int j = 0; j < 4; ++j) acc[i][j] = 0.f;

    for (int k0 = 0; k0 < K; k0 += 16) {
        float4 hv = make_float4(0.f, 0.f, 0.f, 0.f);
        if (!GATHER || hrow) hv = *(const float4*)&hrow[k0 + lq * 4];
        float4 wv = *(const float4*)&w[(size_t)(k0 + wk) * DOUT + cb + wc];
        __syncthreads();
        hs[lq * 4 + 0][lm] = hv.x;
        hs[lq * 4 + 1][lm] = hv.y;
        hs[lq * 4 + 2][lm] = hv.z;
        hs[lq * 4 + 3][lm] = hv.w;
        *(float4*)&wt[wk][wc] = wv;
        __syncthreads();
        #pragma unroll
        for (int kk = 0; kk < 16; ++kk) {
            float4 a  = *(const float4*)&hs[kk][tm * 4];
            float4 bf = *(const float4*)&wt[kk][tn * 4];
            acc[0][0] = fmaf(a.x, bf.x, acc[0][0]);
            acc[0][1] = fmaf(a.x, bf.y, acc[0][1]);
            acc[0][2] = fmaf(a.x, bf.z, acc[0][2]);
            acc[0][3] = fmaf(a.x, bf.w, acc[0][3]);
            acc[1][0] = fmaf(a.y, bf.x, acc[1][0]);
            acc[1][1] = fmaf(a.y, bf.y, acc[1][1]);
            acc[1][2] = fmaf(a.y, bf.z, acc[1][2]);
            acc[1][3] = fmaf(a.y, bf.w, acc[1][3]);
            acc[2][0] = fmaf(a.z, bf.x, acc[2][0]);
            acc[2][1] = fmaf(a.z, bf.y, acc[2][1]);
            acc[2][2] = fmaf(a.z, bf.z, acc[2][2]);
            acc[2][3] = fmaf(a.z, bf.w, acc[2][3]);
            acc[3][0] = fmaf(a.w, bf.x, acc[3][0]);
            acc[3][1] = fmaf(a.w, bf.y, acc[3][1]);
            acc[3][2] = fmaf(a.w, bf.z, acc[3][2]);
            acc[3][3] = fmaf(a.w, bf.w, acc[3][3]);
        }
    }

    float4 bv = *(const float4*)&bias[cb + tn * 4];
    #pragma unroll
    for (int i = 0; i < 4; ++i) {
        float o[4];
        o[0] = fmaxf(acc[i][0] + bv.x, 0.f);
        o[1] = fmaxf(acc[i][1] + bv.y, 0.f);
        o[2] = fmaxf(acc[i][2] + bv.z, 0.f);
        o[3] = fmaxf(acc[i][3] + bv.w, 0.f);
        size_t off = (size_t)(r0 + tm * 4 + i) * DOUT + cb + tn * 4;
        if (SPLIT) {
            ushort4 s0, s1, s2;
            unsigned short* p0[4] = {&s0.x, &s0.y, &s0.z, &s0.w};
            unsigned short* p1[4] = {&s1.x, &s1.y, &s1.z, &s1.w};
            unsigned short* p2[4] = {&s2.x, &s2.y, &s2.z, &s2.w};
            #pragma unroll
            for (int j = 0; j < 4; ++j) {
                unsigned short a0 = f2bf(o[j]);
                float r1v = o[j] - bf2f(a0);
                unsigned short a1 = f2bf(r1v);
                float r2v = r1v - bf2f(a1);
                unsigned short a2 = f2bf(r2v);
                *p0[j] = a0; *p1[j] = a1; *p2[j] = a2;
            }
            *(ushort4*)&hb0[off] = s0;
            *(ushort4*)&hb1[off] = s1;
            *(ushort4*)&hb2[off] = s2;
        } else {
            float4 ov;
            ov.x = o[0]; ov.y = o[1]; ov.z = o[2]; ov.w = o[3];
            *(float4*)&out[off] = ov;
        }
    }
}

// ---------------- kernel 2: bf16x3 MFMA DIFFERENCE-GEMM ----------------------
// decision(e) = sign( h.(w3[:,2e]-w3[:,2e+1]) + bias-diff + gumbel-diff ).
// fp32 emulated as 3 bf16 limbs x 6 MFMA terms (h0w0,h0w1,h1w0,h1w1,h0w2,h2w0)
// into an fp32 accumulator; neglected terms <= ~4*2^-27 * sum|h.wd| ~ 6e-8 abs
// = same class as fp32 reorder noise (no fixup needed).
// Block: 256 thr (4 waves), tile M=64 x N=128 diffs, K-step 32.
// Wave w owns diff cols [w*32, w*32+32) as 2 x 16x16x32 MFMA column frags.
// Grid keeps round-4's XCD swizzle (FETCH 1.37GB -> 0.47GB, keep it).
// mfma_f32_16x16x32_bf16 layouts: A row=l&15, k=8*(l>>4)+j; B k=8*(l>>4)+j,
// col=l&15; D col=l&15, row=4*(l>>4)+r (m89-verified C/D).
__global__ __launch_bounds__(256) void k2_mfma(
    const unsigned short* __restrict__ hb0, const unsigned short* __restrict__ hb1,
    const unsigned short* __restrict__ hb2,
    const float* __restrict__ bw3, const float* __restrict__ bb3,
    const float* __restrict__ sw3, const float* __restrict__ sb3,
    const float* __restrict__ gum,
    const int* __restrict__ meta, const int* __restrict__ borig,
    unsigned char* __restrict__ bits) {
    __shared__ unsigned short As[3][64][32];    // h limbs, [row][k], 64B rows
    __shared__ unsigned short Bs[3][128][32];   // wd limbs, [col][k], k-granule XOR-swz

    int tid = threadIdx.x;
    int wgid = blockIdx.x;              // 0..2303, XCD-aware map (round-4 proven)
    int xr  = wgid & 7;
    int s_  = wgid >> 3;
    int by  = s_ % 9;                   // row tile 0..8
    int q   = s_ / 9;                   // col chunk 0..31
    int bx  = q * 8 + xr;               // col tile 0..255
    if (bx >= 255) return;              // uniform per block: safe with barriers

    int r0 = by * 64;
    int cb = bx * 256;                  // w3 column base
    int db = bx * 128;                  // diff (e-pair) column base
    int S = meta[0];
    bool big = (r0 < S);
    const float* w3 = big ? bw3 : sw3;
    const float* b3 = big ? bb3 : sb3;

    int lane = tid & 63;
    int wid  = tid >> 6;                // wave 0..3 -> diff cols wid*32..+31
    int l15  = lane & 15;
    int lg   = lane >> 4;               // 0..3

    // staging indices
    int arow = tid >> 2;                // A: h row 0..63
    int aq   = (tid & 3) * 8;           // A: k offset (8 bf16 = 16B)
    int bkk  = tid >> 3;                // B: k row 0..31
    int bc8  = tid & 7;                 // B: col-group; w3 cols bc8*32..+31
    int c3w  = bc8 & 3;                 // write-side granule XOR key ((colv>>4)&3)
    int kidx = (bkk & 7) | (((bkk >> 3) ^ c3w) << 3);  // swizzled k position

    f32x4 acc[4][2];
    #pragma unroll
    for (int m = 0; m < 4; ++m)
        #pragma unroll
        for (int n = 0; n < 2; ++n) acc[m][n] = (f32x4)0.f;

    const unsigned short* ha0 = &hb0[(size_t)(r0 + arow) * D3 + aq];
    const unsigned short* ha1 = &hb1[(size_t)(r0 + arow) * D3 + aq];
    const unsigned short* ha2 = &hb2[(size_t)(r0 + arow) * D3 + aq];

    for (int k0 = 0; k0 < D3; k0 += 32) {
        // ---- global loads ----
        uint4 av0 = *(const uint4*)&ha0[k0];
        uint4 av1 = *(const uint4*)&ha1[k0];
        uint4 av2 = *(const uint4*)&ha2[k0];
        const float* wr = &w3[(size_t)(k0 + bkk) * OUTCOLS + cb + bc8 * 32];
        float4 wv0 = *(const float4*)&wr[0];
        float4 wv1 = *(const float4*)&wr[4];
        float4 wv2 = *(const float4*)&wr[8];
        float4 wv3 = *(const float4*)&wr[12];
        float4 wv4 = *(const float4*)&wr[16];
        float4 wv5 = *(const float4*)&wr[20];
        float4 wv6 = *(const float4*)&wr[24];
        float4 wv7 = *(const float4*)&wr[28];
        __syncthreads();                 // previous iter's LDS reads done
        // ---- A stage: 16B vector stores ----
        *(uint4*)&As[0][arow][aq] = av0;
        *(uint4*)&As[1][arow][aq] = av1;
        *(uint4*)&As[2][arow][aq] = av2;
        // ---- B stage: diff + 3-limb split, b16 stores (swz k-granule) ----
        {
            float d[16] = {
                wv0.x - wv0.y, wv0.z - wv0.w, wv1.x - wv1.y, wv1.z - wv1.w,
                wv2.x - wv2.y, wv2.z - wv2.w, wv3.x - wv3.y, wv3.z - wv3.w,
                wv4.x - wv4.y, wv4.z - wv4.w, wv5.x - wv5.y, wv5.z - wv5.w,
                wv6.x - wv6.y, wv6.z - wv6.w, wv7.x - wv7.y, wv7.z - wv7.w };
            #pragma unroll
            for (int i = 0; i < 16; ++i) {
                int colv = bc8 * 16 + i;
                float dv = d[i];
                unsigned short d0 = f2bf(dv);
                float r1v = dv - bf2f(d0);
                unsigned short d1 = f2bf(r1v);
                float r2v = r1v - bf2f(d1);
                unsigned short d2 = f2bf(r2v);
                Bs[0][colv][kidx] = d0;
                Bs[1][colv][kidx] = d1;
                Bs[2][colv][kidx] = d2;
            }
        }
        __syncthreads();
        // ---- fragments ----
        bf16x8 af0[4], af1[4], af2[4];
        #pragma unroll
        for (int m = 0; m < 4; ++m) {
            af0[m] = *(const bf16x8*)&As[0][m * 16 + l15][lg * 8];
            af1[m] = *(const bf16x8*)&As[1][m * 16 + l15][lg * 8];
            af2[m] = *(const bf16x8*)&As[2][m * 16 + l15][lg * 8];
        }
        bf16x8 bf0[2], bf1[2], bf2v[2];
        #pragma unroll
        for (int n = 0; n < 2; ++n) {
            int col = wid * 32 + n * 16 + l15;
            int kb  = (lg ^ ((col >> 4) & 3)) * 8;   // undo write swizzle
            bf0[n]  = *(const bf16x8*)&Bs[0][col][kb];
            bf1[n]  = *(const bf16x8*)&Bs[1][col][kb];
            bf2v[n] = *(const bf16x8*)&Bs[2][col][kb];
        }
        // ---- 6-term MFMA ----
        #pragma unroll
        for (int m = 0; m < 4; ++m)
            #pragma unroll
            for (int n = 0; n < 2; ++n) {
                f32x4 c = acc[m][n];
                c = __builtin_amdgcn_mfma_f32_16x16x32_bf16(af0[m], bf0[n],  c, 0, 0, 0);
                c = __builtin_amdgcn_mfma_f32_16x16x32_bf16(af0[m], bf1[n],  c, 0, 0, 0);
                c = __builtin_amdgcn_mfma_f32_16x16x32_bf16(af1[m], bf0[n],  c, 0, 0, 0);
                c = __builtin_amdgcn_mfma_f32_16x16x32_bf16(af1[m], bf1[n],  c, 0, 0, 0);
                c = __builtin_amdgcn_mfma_f32_16x16x32_bf16(af0[m], bf2v[n], c, 0, 0, 0);
                c = __builtin_amdgcn_mfma_f32_16x16x32_bf16(af2[m], bf0[n],  c, 0, 0, 0);
                acc[m][n] = c;
            }
    }

    // ---- epilogue: bias-diff + gumbel-diff, compare, store bit bytes ----
    #pragma unroll
    for (int n = 0; n < 2; ++n) {
        int colg = db + wid * 32 + n * 16 + l15;     // global e-pair index
        float2 bv = *(const float2*)&b3[2 * colg];
        float bd = bv.x - bv.y;
        #pragma unroll
        for (int m = 0; m < 4; ++m) {
            #pragma unroll
            for (int r = 0; r < 4; ++r) {
                int slot = r0 + m * 16 + lg * 4 + r;
                int b = borig[slot];
                if (b < 0) continue;
                float2 gv = *(const float2*)&gum[(size_t)b * OUTCOLS + 2 * colg];
                float g = acc[m][n][r] + bd + (gv.x - gv.y);
                bits[(size_t)b * E_PAIRS + colg] = (g >= 0.f) ? 1 : 0;
            }
        }
    }
}

// ---------------- kernel 3: tiled bit->fp32 expansion with LDS transpose ------
__global__ __launch_bounds__(256) void k3_expand(
    const unsigned char* __restrict__ bits, float* __restrict__ out) {
    __shared__ unsigned char L[64][68];   // stride 68 bytes
    const int ti_tab[10] = {0,0,0,0,1,1,1,2,2,3};
    const int tj_tab[10] = {0,1,2,3,1,2,3,2,3,3};
    int p = blockIdx.x;                   // 0..9
    int b = blockIdx.y;                   // 0..511
    int ti = ti_tab[p], tj = tj_tab[p];
    int t = threadIdx.x;

    // ---- stage bits: row r (i = ti*64+r), 16 bytes per thread ----
    {
        int r = t >> 2;                   // 0..63
        int q = t & 3;                    // 0..3
        int i = ti * 64 + r;
        // e(i,j) = i*(511-i)/2 + j - i - 1  (valid for j > i)
        long base = (long)b * E_PAIRS + (long)i * (511 - i) / 2 - i - 1;
        int j0 = tj * 64 + q * 16;
        #pragma unroll
        for (int k = 0; k < 16; ++k) {
            int j = j0 + k;
            unsigned char v = (j > i) ? bits[base + j] : (unsigned char)0;
            L[r][q * 16 + k] = v;
        }
    }
    __syncthreads();

    int h  = t >> 4;                      // 0..15  (row within group of 16)
    int w4 = (t & 15) * 4;                // col base, float4 granularity

    // ---- direct tile: out[b][ti*64+ii][tj*64 + w4 .. +3] ----
    {
        #pragma unroll
        for (int rr = 0; rr < 4; ++rr) {
            int ii = rr * 16 + h;
            int i_ = ti * 64 + ii;
            float4 v;
            if (ti == tj) {
                int jj;
                jj = w4 + 0; v.x = (jj > ii) ? (float)L[ii][jj] : (jj < ii ? (float)L[jj][ii] : 0.f);
                jj = w4 + 1; v.y = (jj > ii) ? (float)L[ii][jj] : (jj < ii ? (float)L[jj][ii] : 0.f);
                jj = w4 + 2; v.z = (jj > ii) ? (float)L[ii][jj] : (jj < ii ? (float)L[jj][ii] : 0.f);
                jj = w4 + 3; v.w = (jj > ii) ? (float)L[ii][jj] : (jj < ii ? (float)L[jj][ii] : 0.f);
            } else {
                v.x = (float)L[ii][w4 + 0];
                v.y = (float)L[ii][w4 + 1];
                v.z = (float)L[ii][w4 + 2];
                v.w = (float)L[ii][w4 + 3];
            }
            size_t o = (((size_t)b * 256 + i_) * 256) + tj * 64 + w4;
            *(float4*)&out[o] = v;
        }
    }

    // ---- mirrored tile (off-diagonal only): out[b][tj*64+jj][ti*64 + w4 ..] ----
    if (ti != tj) {
        #pragma unroll
        for (int rr = 0; rr < 4; ++rr) {
            int jj = rr * 16 + h;
            int j_ = tj * 64 + jj;
            float4 v;                      // value(i=col, j=row) = L[col_local][jj]
            v.x = (float)L[w4 + 0][jj];
            v.y = (float)L[w4 + 1][jj];
            v.z = (float)L[w4 + 2][jj];
            v.w = (float)L[w4 + 3][jj];
            size_t o = (((size_t)b * 256 + j_) * 256) + ti * 64 + w4;
            *(float4*)&out[o] = v;
        }
    }
}

// -----------------------------------------------------------------------------
extern "C" void kernel_launch(void* const* d_in, const int* in_sizes, int n_in,
                              void* d_out, int out_size, void* d_ws, size_t ws_size,
                              hipStream_t stream) {
    const float* x   = (const float*)d_in[0];
    const float* gum = (const float*)d_in[1];
    const float* bw0 = (const float*)d_in[2];  const float* bb0 = (const float*)d_in[3];
    const float* sw0 = (const float*)d_in[4];  const float* sb0 = (const float*)d_in[5];
    const float* bw1 = (const float*)d_in[6];  const float* bb1 = (const float*)d_in[7];
    const float* sw1 = (const float*)d_in[8];  const float* sb1 = (const float*)d_in[9];
    const float* bw2 = (const float*)d_in[10]; const float* bb2 = (const float*)d_in[11];
    const float* sw2 = (const float*)d_in[12]; const float* sb2 = (const float*)d_in[13];
    const float* bw3 = (const float*)d_in[14]; const float* bb3 = (const float*)d_in[15];
    const float* sw3 = (const float*)d_in[16]; const float* sb3 = (const float*)d_in[17];

    char* ws = (char*)d_ws;
    int*   meta  = (int*)ws;                               // 64 B
    int*   borig = (int*)(ws + 64);                        // 576 ints
    float* act1  = (float*)(ws + 4096);                    // 576*256 fp32
    float* act2  = (float*)(ws + 593920);                  // 576*512 fp32
    unsigned short* hb0 = (unsigned short*)(ws + 1773568); // 576*1024 bf16
    unsigned short* hb1 = (unsigned short*)(ws + 2953216);
    unsigned short* hb2 = (unsigned short*)(ws + 4132864);
    unsigned char* bits = (unsigned char*)(ws + 5312512);  // 512*32640 bytes
    float* out = (float*)d_out;                            // total ws use ~22.0 MB

    k0_sort<<<1, SLOTS, 0, stream>>>(x, meta, borig);
    k1_gemm<true,  COND, D1, false><<<dim3(9, D1 / 64), 256, 0, stream>>>(
        x,    bw0, bb0, sw0, sb0, meta, borig, act1, 0, 0, 0);
    k1_gemm<false, D1,   D2, false><<<dim3(9, D2 / 64), 256, 0, stream>>>(
        act1, bw1, bb1, sw1, sb1, meta, borig, act2, 0, 0, 0);
    k1_gemm<false, D2,   D3, true><<<dim3(9, D3 / 64), 256, 0, stream>>>(
        act2, bw2, bb2, sw2, sb2, meta, borig, (float*)0, hb0, hb1, hb2);
    k2_mfma<<<2304, 256, 0, stream>>>(hb0, hb1, hb2, bw3, bb3, sw3, sb3, gum,
                                      meta, borig, bits);
    k3_expand<<<dim3(10, BATCH), 256, 0, stream>>>(bits, out);
}

// Round 6
// 1020.444 us; speedup vs baseline: 1.1131x; 1.0292x over previous
//
#include <hip/hip_runtime.h>

#define N_NODES 256
#define COND    64
#define E_PAIRS 32640
#define OUTCOLS 65280
#define BATCH   512
#define SLOTS   576    // 9 row-tiles of 64 (big rows padded to 64, then small, then pad)
#define D1      256
#define D2      512
#define D3      1024

typedef __attribute__((ext_vector_type(8))) short bf16x8;   // MFMA A/B frag (4 VGPR)
typedef __attribute__((ext_vector_type(4))) float f32x4;    // MFMA C/D frag
typedef __attribute__((ext_vector_type(4))) unsigned int u32x4;

static __device__ __forceinline__ unsigned short f2bf(float f) {   // RNE float->bf16
    unsigned int u = __float_as_uint(f);
    u += 0x7FFF + ((u >> 16) & 1);
    return (unsigned short)(u >> 16);
}
static __device__ __forceinline__ float bf2f(unsigned short h) {
    return __uint_as_float(((unsigned int)h) << 16);
}

// ---------------- kernel 0: ballot-based stable sort into 64-aligned slots ---
__global__ void k0_sort(const float* __restrict__ x, int* __restrict__ meta,
                        int* __restrict__ borig) {
    __shared__ int wc[9];
    int t = threadIdx.x;                 // blockDim = 576 (9 waves)
    if (t < SLOTS) borig[t] = -1;        // pad default
    int m = 0;
    if (t < BATCH) m = (x[t * COND] > 0.0f) ? 1 : 0;
    unsigned long long bm = __ballot(m);
    int wave = t >> 6;
    int lane = t & 63;
    int lanePre = __popcll(bm & ((1ull << lane) - 1ull));
    if (lane == 0) wc[wave] = __popcll(bm);
    __syncthreads();
    int nbig = 0, preBig = 0;
    #pragma unroll
    for (int w = 0; w < 8; ++w) {        // waves 0..7 cover t<512
        int c = wc[w];
        if (w < wave) preBig += c;
        nbig += c;
    }
    int S = (nbig + 63) & ~63;           // big slots [0,S), small [S, S+nsmall)
    if (t < BATCH) {
        int onesBefore = preBig + lanePre;
        int slot = m ? onesBefore : (S + (t - onesBefore));
        borig[slot] = t;
    }
    if (t == 0) meta[0] = S;
}

// ---------------- kernel 1: MLP layers as tiled GEMMs ------------------------
// 64x64 tile, 256 threads, 4x4 per thread, ReLU fused.
// GATHER (layer 0): rows via borig. SPLIT (layer 2): write h as 3 bf16 limbs
// DIRECTLY IN MFMA A-FRAGMENT LANE ORDER:
//   hbA[(by*32+kk)*3 + limb][m][lane][j]  (lane = lg*16+l15, 8 shorts/lane)
// so k2 loads A-frags as coalesced 1KB dwordx4 with no LDS staging at all.
template <bool GATHER, int K, int DOUT, bool SPLIT>
__global__ __launch_bounds__(256) void k1_gemm(
    const float* __restrict__ in,
    const float* __restrict__ wbig, const float* __restrict__ bbig,
    const float* __restrict__ wsml, const float* __restrict__ bsml,
    const int* __restrict__ meta, const int* __restrict__ borig,
    float* __restrict__ out, unsigned short* __restrict__ hbA) {
    __shared__ float hs[16][64 + 4];     // transposed act tile
    __shared__ float wt[16][64 + 4];     // weight tile
    int tid = threadIdx.x;
    int by = blockIdx.x;                 // row tile 0..8
    int bx = blockIdx.y;                 // col tile
    int r0 = by * 64;
    int cb = bx * 64;
    int S = meta[0];
    bool big = (r0 < S);                 // row tiles are expert-uniform
    const float* w = big ? wbig : wsml;
    const float* bias = big ? bbig : bsml;

    int lm = tid >> 2;                   // act-load row 0..63
    int lq = tid & 3;                    // act-load k quad
    int wk = tid >> 4;                   // w-load k row 0..15
    int wc = (tid & 15) * 4;             // w-load col offset

    int tm = tid >> 4;                   // 0..15 : rows tm*4..+3
    int tn = tid & 15;                   // 0..15 : cols tn*4..+3

    const float* hrow;
    if (GATHER) {
        int b = borig[r0 + lm];
        hrow = (b >= 0) ? &in[(size_t)b * K] : (const float*)0;
    } else {
        hrow = &in[(size_t)(r0 + lm) * K];   // pad rows hold garbage; harmless
    }

    float acc[4][4];
    #pragma unroll
    for (int i = 0; i < 4; ++i)
        #pragma unroll
        for (int j = 0; j < 4; ++j) acc[i][j] = 0.f;

    for (int k0 = 0; k0 < K; k0 += 16) {
        float4 hv = make_float4(0.f, 0.f, 0.f, 0.f);
        if (!GATHER || hrow) hv = *(const float4*)&hrow[k0 + lq * 4];
        float4 wv = *(const float4*)&w[(size_t)(k0 + wk) * DOUT + cb + wc];
        __syncthreads();
        hs[lq * 4 + 0][lm] = hv.x;
        hs[lq * 4 + 1][lm] = hv.y;
        hs[lq * 4 + 2][lm] = hv.z;
        hs[lq * 4 + 3][lm] = hv.w;
        *(float4*)&wt[wk][wc] = wv;
        __syncthreads();
        #pragma unroll
        for (int kk = 0; kk < 16; ++kk) {
            float4 a  = *(const float4*)&hs[kk][tm * 4];
            float4 bf = *(const float4*)&wt[kk][tn * 4];
            acc[0][0] = fmaf(a.x, bf.x, acc[0][0]);
            acc[0][1] = fmaf(a.x, bf.y, acc[0][1]);
            acc[0][2] = fmaf(a.x, bf.z, acc[0][2]);
            acc[0][3] = fmaf(a.x, bf.w, acc[0][3]);
            acc[1][0] = fmaf(a.y, bf.x, acc[1][0]);
            acc[1][1] = fmaf(a.y, bf.y, acc[1][1]);
            acc[1][2] = fmaf(a.y, bf.z, acc[1][2]);
            acc[1][3] = fmaf(a.y, bf.w, acc[1][3]);
            acc[2][0] = fmaf(a.z, bf.x, acc[2][0]);
            acc[2][1] = fmaf(a.z, bf.y, acc[2][1]);
            acc[2][2] = fmaf(a.z, bf.z, acc[2][2]);
            acc[2][3] = fmaf(a.z, bf.w, acc[2][3]);
            acc[3][0] = fmaf(a.w, bf.x, acc[3][0]);
            acc[3][1] = fmaf(a.w, bf.y, acc[3][1]);
            acc[3][2] = fmaf(a.w, bf.z, acc[3][2]);
            acc[3][3] = fmaf(a.w, bf.w, acc[3][3]);
        }
    }

    float4 bv = *(const float4*)&bias[cb + tn * 4];
    #pragma unroll
    for (int i = 0; i < 4; ++i) {
        float o[4];
        o[0] = fmaxf(acc[i][0] + bv.x, 0.f);
        o[1] = fmaxf(acc[i][1] + bv.y, 0.f);
        o[2] = fmaxf(acc[i][2] + bv.z, 0.f);
        o[3] = fmaxf(acc[i][3] + bv.w, 0.f);
        if (SPLIT) {
            // element (row, k): frag addr = ((by*32+kk)*3+limb)*2048 + m*512
            //                               + (lg*16 + l15)*8 + j   [shorts]
            int row = r0 + tm * 4 + i;
            int by_ = row >> 6, rl = row & 63;
            int mfr = rl >> 4, p15 = rl & 15;
            int kt  = cb + tn * 4;           // 4 consecutive k, same lg group
            int kk  = kt >> 5, lgk = (kt >> 3) & 3, j0 = kt & 7;
            size_t base = (size_t)(by_ * 32 + kk) * 6144 + (size_t)mfr * 512
                        + (size_t)(lgk * 16 + p15) * 8 + j0;
            ushort4 s0, s1, s2;
            unsigned short* q0[4] = {&s0.x, &s0.y, &s0.z, &s0.w};
            unsigned short* q1[4] = {&s1.x, &s1.y, &s1.z, &s1.w};
            unsigned short* q2[4] = {&s2.x, &s2.y, &s2.z, &s2.w};
            #pragma unroll
            for (int j = 0; j < 4; ++j) {
                unsigned short a0 = f2bf(o[j]);
                float r1v = o[j] - bf2f(a0);
                unsigned short a1 = f2bf(r1v);
                float r2v = r1v - bf2f(a1);
                *q0[j] = a0; *q1[j] = a1; *q2[j] = f2bf(r2v);
            }
            *(ushort4*)&hbA[base]        = s0;
            *(ushort4*)&hbA[base + 2048] = s1;
            *(ushort4*)&hbA[base + 4096] = s2;
        } else {
            float4 ov;
            ov.x = o[0]; ov.y = o[1]; ov.z = o[2]; ov.w = o[3];
            *(float4*)&out[(size_t)(r0 + tm * 4 + i) * DOUT + cb + tn * 4] = ov;
        }
    }
}

// ---------------- kernel 2: bf16x3 MFMA DIFF-GEMM, ZERO LDS / ZERO BARRIERS --
// Round-5 failure mode: 2 barriers + 48 scalar ds_write_b16 per thread per
// K-step -> MfmaUtil 19 / VALU 25 / 4.9e7 bank conflicts, all pipes idle.
// Fix: A-frags pre-arranged in lane order by k1 (coalesced 1KB L2 loads);
// B-frags are wave-private (waves own disjoint cols) -> each lane loads its
// own 16 w3 values, diffs+splits in registers, feeds MFMA. No __syncthreads.
// Grid keeps round-4 XCD swizzle (FETCH 1.37GB -> 0.47GB proven).
__global__ __launch_bounds__(256, 2) void k2_mfma(
    const unsigned short* __restrict__ hbA,
    const float* __restrict__ bw3, const float* __restrict__ bb3,
    const float* __restrict__ sw3, const float* __restrict__ sb3,
    const float* __restrict__ gum,
    const int* __restrict__ meta, const int* __restrict__ borig,
    unsigned char* __restrict__ bits) {
    int tid = threadIdx.x;
    int wgid = blockIdx.x;              // 0..2303
    int xr  = wgid & 7;
    int s_  = wgid >> 3;
    int by  = s_ % 9;                   // row tile 0..8
    int q   = s_ / 9;                   // col chunk 0..31
    int bx  = q * 8 + xr;               // col tile 0..255
    if (bx >= 255) return;              // no barriers -> early exit trivially safe

    int r0 = by * 64;
    int db = bx * 128;                  // diff (e-pair) column base
    int S = meta[0];
    bool big = (r0 < S);
    const float* w3 = big ? bw3 : sw3;
    const float* b3 = big ? bb3 : sb3;

    int lane = tid & 63;
    int wid  = tid >> 6;                // wave 0..3 -> diff cols wid*32..+31
    int l15  = lane & 15;
    int lg   = lane >> 4;               // k-group 0..3

    int colg0 = db + wid * 32 + l15;    // this lane's n=0 diff column

    f32x4 acc[4][2];
    #pragma unroll
    for (int m = 0; m < 4; ++m)
        #pragma unroll
        for (int n = 0; n < 2; ++n) acc[m][n] = (f32x4)0.f;

    const unsigned short* ap0 = hbA + (size_t)(by * 32) * 6144 + (size_t)lane * 8;

    for (int kk = 0; kk < 32; ++kk) {
        // ---- A fragments: 12 coalesced 16B loads (1KB/wave-instr, L2-hot) ----
        const unsigned short* ap = ap0 + (size_t)kk * 6144;
        bf16x8 af[3][4];
        #pragma unroll
        for (int limb = 0; limb < 3; ++limb)
            #pragma unroll
            for (int m = 0; m < 4; ++m)
                af[limb][m] = *(const bf16x8*)(ap + limb * 2048 + m * 512);

        // ---- B fragments: per-lane loads + in-register diff + 3-limb split ----
        u32x4 fr0[2], fr1[2], fr2[2];
        #pragma unroll
        for (int n = 0; n < 2; ++n) {
            const float* wp = w3 + (size_t)(kk * 32 + lg * 8) * OUTCOLS
                                 + 2 * (colg0 + n * 16);
            float d[8];
            #pragma unroll
            for (int j = 0; j < 8; ++j) {
                float2 v = *(const float2*)(wp + (size_t)j * OUTCOLS);
                d[j] = v.x - v.y;
            }
            #pragma unroll
            for (int w = 0; w < 4; ++w) {
                float dA = d[2 * w], dB = d[2 * w + 1];
                unsigned short aL = f2bf(dA), aH = f2bf(dB);
                fr0[n][w] = (unsigned int)aL | ((unsigned int)aH << 16);
                float rA = dA - bf2f(aL), rB = dB - bf2f(aH);
                unsigned short bL = f2bf(rA), bH = f2bf(rB);
                fr1[n][w] = (unsigned int)bL | ((unsigned int)bH << 16);
                float sA = rA - bf2f(bL), sB = rB - bf2f(bH);
                fr2[n][w] = (unsigned int)f2bf(sA) | ((unsigned int)f2bf(sB) << 16);
            }
        }

        // ---- 6-term MFMA (h0w0,h0w1,h1w0,h1w1,h0w2,h2w0) ----
        #pragma unroll
        for (int n = 0; n < 2; ++n) {
            bf16x8 b0 = __builtin_bit_cast(bf16x8, fr0[n]);
            bf16x8 b1 = __builtin_bit_cast(bf16x8, fr1[n]);
            bf16x8 b2 = __builtin_bit_cast(bf16x8, fr2[n]);
            #pragma unroll
            for (int m = 0; m < 4; ++m) {
                f32x4 c = acc[m][n];
                c = __builtin_amdgcn_mfma_f32_16x16x32_bf16(af[0][m], b0, c, 0, 0, 0);
                c = __builtin_amdgcn_mfma_f32_16x16x32_bf16(af[0][m], b1, c, 0, 0, 0);
                c = __builtin_amdgcn_mfma_f32_16x16x32_bf16(af[1][m], b0, c, 0, 0, 0);
                c = __builtin_amdgcn_mfma_f32_16x16x32_bf16(af[1][m], b1, c, 0, 0, 0);
                c = __builtin_amdgcn_mfma_f32_16x16x32_bf16(af[0][m], b2, c, 0, 0, 0);
                c = __builtin_amdgcn_mfma_f32_16x16x32_bf16(af[2][m], b0, c, 0, 0, 0);
                acc[m][n] = c;
            }
        }
    }

    // ---- epilogue: bias-diff + gumbel-diff, compare, store bit bytes ----
    #pragma unroll
    for (int n = 0; n < 2; ++n) {
        int colg = db + wid * 32 + n * 16 + l15;     // global e-pair index
        float2 bv = *(const float2*)&b3[2 * colg];
        float bd = bv.x - bv.y;
        #pragma unroll
        for (int m = 0; m < 4; ++m) {
            #pragma unroll
            for (int r = 0; r < 4; ++r) {
                int slot = r0 + m * 16 + lg * 4 + r;
                int b = borig[slot];
                if (b < 0) continue;
                float2 gv = *(const float2*)&gum[(size_t)b * OUTCOLS + 2 * colg];
                float g = acc[m][n][r] + bd + (gv.x - gv.y);
                bits[(size_t)b * E_PAIRS + colg] = (g >= 0.f) ? 1 : 0;
            }
        }
    }
}

// ---------------- kernel 3: tiled bit->fp32 expansion with LDS transpose ------
__global__ __launch_bounds__(256) void k3_expand(
    const unsigned char* __restrict__ bits, float* __restrict__ out) {
    __shared__ unsigned char L[64][68];   // stride 68 bytes
    const int ti_tab[10] = {0,0,0,0,1,1,1,2,2,3};
    const int tj_tab[10] = {0,1,2,3,1,2,3,2,3,3};
    int p = blockIdx.x;                   // 0..9
    int b = blockIdx.y;                   // 0..511
    int ti = ti_tab[p], tj = tj_tab[p];
    int t = threadIdx.x;

    // ---- stage bits: row r (i = ti*64+r), 16 bytes per thread ----
    {
        int r = t >> 2;                   // 0..63
        int q = t & 3;                    // 0..3
        int i = ti * 64 + r;
        // e(i,j) = i*(511-i)/2 + j - i - 1  (valid for j > i)
        long base = (long)b * E_PAIRS + (long)i * (511 - i) / 2 - i - 1;
        int j0 = tj * 64 + q * 16;
        #pragma unroll
        for (int k = 0; k < 16; ++k) {
            int j = j0 + k;
            unsigned char v = (j > i) ? bits[base + j] : (unsigned char)0;
            L[r][q * 16 + k] = v;
        }
    }
    __syncthreads();

    int h  = t >> 4;                      // 0..15  (row within group of 16)
    int w4 = (t & 15) * 4;                // col base, float4 granularity

    // ---- direct tile: out[b][ti*64+ii][tj*64 + w4 .. +3] ----
    {
        #pragma unroll
        for (int rr = 0; rr < 4; ++rr) {
            int ii = rr * 16 + h;
            int i_ = ti * 64 + ii;
            float4 v;
            if (ti == tj) {
                int jj;
                jj = w4 + 0; v.x = (jj > ii) ? (float)L[ii][jj] : (jj < ii ? (float)L[jj][ii] : 0.f);
                jj = w4 + 1; v.y = (jj > ii) ? (float)L[ii][jj] : (jj < ii ? (float)L[jj][ii] : 0.f);
                jj = w4 + 2; v.z = (jj > ii) ? (float)L[ii][jj] : (jj < ii ? (float)L[jj][ii] : 0.f);
                jj = w4 + 3; v.w = (jj > ii) ? (float)L[ii][jj] : (jj < ii ? (float)L[jj][ii] : 0.f);
            } else {
                v.x = (float)L[ii][w4 + 0];
                v.y = (float)L[ii][w4 + 1];
                v.z = (float)L[ii][w4 + 2];
                v.w = (float)L[ii][w4 + 3];
            }
            size_t o = (((size_t)b * 256 + i_) * 256) + tj * 64 + w4;
            *(float4*)&out[o] = v;
        }
    }

    // ---- mirrored tile (off-diagonal only): out[b][tj*64+jj][ti*64 + w4 ..] ----
    if (ti != tj) {
        #pragma unroll
        for (int rr = 0; rr < 4; ++rr) {
            int jj = rr * 16 + h;
            int j_ = tj * 64 + jj;
            float4 v;                      // value(i=col, j=row) = L[col_local][jj]
            v.x = (float)L[w4 + 0][jj];
            v.y = (float)L[w4 + 1][jj];
            v.z = (float)L[w4 + 2][jj];
            v.w = (float)L[w4 + 3][jj];
            size_t o = (((size_t)b * 256 + j_) * 256) + ti * 64 + w4;
            *(float4*)&out[o] = v;
        }
    }
}

// -----------------------------------------------------------------------------
extern "C" void kernel_launch(void* const* d_in, const int* in_sizes, int n_in,
                              void* d_out, int out_size, void* d_ws, size_t ws_size,
                              hipStream_t stream) {
    const float* x   = (const float*)d_in[0];
    const float* gum = (const float*)d_in[1];
    const float* bw0 = (const float*)d_in[2];  const float* bb0 = (const float*)d_in[3];
    const float* sw0 = (const float*)d_in[4];  const float* sb0 = (const float*)d_in[5];
    const float* bw1 = (const float*)d_in[6];  const float* bb1 = (const float*)d_in[7];
    const float* sw1 = (const float*)d_in[8];  const float* sb1 = (const float*)d_in[9];
    const float* bw2 = (const float*)d_in[10]; const float* bb2 = (const float*)d_in[11];
    const float* sw2 = (const float*)d_in[12]; const float* sb2 = (const float*)d_in[13];
    const float* bw3 = (const float*)d_in[14]; const float* bb3 = (const float*)d_in[15];
    const float* sw3 = (const float*)d_in[16]; const float* sb3 = (const float*)d_in[17];

    char* ws = (char*)d_ws;
    int*   meta  = (int*)ws;                               // 64 B
    int*   borig = (int*)(ws + 64);                        // 576 ints
    float* act1  = (float*)(ws + 4096);                    // 576*256 fp32
    float* act2  = (float*)(ws + 593920);                  // 576*512 fp32
    unsigned short* hbA = (unsigned short*)(ws + 1773568); // 576*1024*3 bf16 frag-order
    unsigned char* bits = (unsigned char*)(ws + 5312512);  // 512*32640 bytes
    float* out = (float*)d_out;                            // total ws use ~22.0 MB

    k0_sort<<<1, SLOTS, 0, stream>>>(x, meta, borig);
    k1_gemm<true,  COND, D1, false><<<dim3(9, D1 / 64), 256, 0, stream>>>(
        x,    bw0, bb0, sw0, sb0, meta, borig, act1, 0);
    k1_gemm<false, D1,   D2, false><<<dim3(9, D2 / 64), 256, 0, stream>>>(
        act1, bw1, bb1, sw1, sb1, meta, borig, act2, 0);
    k1_gemm<false, D2,   D3, true><<<dim3(9, D3 / 64), 256, 0, stream>>>(
        act2, bw2, bb2, sw2, sb2, meta, borig, (float*)0, hbA);
    k2_mfma<<<2304, 256, 0, stream>>>(hbA, bw3, bb3, sw3, sb3, gum,
                                      meta, borig, bits);
    k3_expand<<<dim3(10, BATCH), 256, 0, stream>>>(bits, out);
}

// Round 7
// 992.890 us; speedup vs baseline: 1.1440x; 1.0278x over previous
//
#include <hip/hip_runtime.h>

#define N_NODES 256
#define COND    64
#define E_PAIRS 32640
#define OUTCOLS 65280
#define BATCH   512
#define SLOTS   576    // 9 row-tiles of 64 (big rows padded to 64, then small, then pad)
#define D1      256
#define D2      512
#define D3      1024

typedef __attribute__((ext_vector_type(8))) short bf16x8;   // MFMA A/B frag (4 VGPR)
typedef __attribute__((ext_vector_type(4))) float f32x4;    // MFMA C/D frag
typedef __attribute__((ext_vector_type(4))) unsigned int u32x4;

static __device__ __forceinline__ unsigned short f2bf(float f) {   // RNE float->bf16
    unsigned int u = __float_as_uint(f);
    u += 0x7FFF + ((u >> 16) & 1);
    return (unsigned short)(u >> 16);
}
static __device__ __forceinline__ float bf2f(unsigned short h) {
    return __uint_as_float(((unsigned int)h) << 16);
}

// ---------------- kernel 0: ballot-based stable sort into 64-aligned slots ---
__global__ void k0_sort(const float* __restrict__ x, int* __restrict__ meta,
                        int* __restrict__ borig) {
    __shared__ int wc[9];
    int t = threadIdx.x;                 // blockDim = 576 (9 waves)
    if (t < SLOTS) borig[t] = -1;        // pad default
    int m = 0;
    if (t < BATCH) m = (x[t * COND] > 0.0f) ? 1 : 0;
    unsigned long long bm = __ballot(m);
    int wave = t >> 6;
    int lane = t & 63;
    int lanePre = __popcll(bm & ((1ull << lane) - 1ull));
    if (lane == 0) wc[wave] = __popcll(bm);
    __syncthreads();
    int nbig = 0, preBig = 0;
    #pragma unroll
    for (int w = 0; w < 8; ++w) {        // waves 0..7 cover t<512
        int c = wc[w];
        if (w < wave) preBig += c;
        nbig += c;
    }
    int S = (nbig + 63) & ~63;           // big slots [0,S), small [S, S+nsmall)
    if (t < BATCH) {
        int onesBefore = preBig + lanePre;
        int slot = m ? onesBefore : (S + (t - onesBefore));
        borig[slot] = t;
    }
    if (t == 0) meta[0] = S;
}

// ---------------- kernel 1: MLP layers as tiled GEMMs ------------------------
// 64x64 tile, 256 threads, 4x4 per thread, ReLU fused.
// GATHER (layer 0): rows via borig. SPLIT (layer 2): write h as 3 bf16 limbs
// DIRECTLY IN MFMA A-FRAGMENT LANE ORDER:
//   hbA[(by*32+kk)*3 + limb][m][lane][j]  (lane = lg*16+l15, 8 shorts/lane)
// so k2 loads A-frags as coalesced 1KB dwordx4 with no LDS staging at all.
template <bool GATHER, int K, int DOUT, bool SPLIT>
__global__ __launch_bounds__(256) void k1_gemm(
    const float* __restrict__ in,
    const float* __restrict__ wbig, const float* __restrict__ bbig,
    const float* __restrict__ wsml, const float* __restrict__ bsml,
    const int* __restrict__ meta, const int* __restrict__ borig,
    float* __restrict__ out, unsigned short* __restrict__ hbA) {
    __shared__ float hs[16][64 + 4];     // transposed act tile
    __shared__ float wt[16][64 + 4];     // weight tile
    int tid = threadIdx.x;
    int by = blockIdx.x;                 // row tile 0..8
    int bx = blockIdx.y;                 // col tile
    int r0 = by * 64;
    int cb = bx * 64;
    int S = meta[0];
    bool big = (r0 < S);                 // row tiles are expert-uniform
    const float* w = big ? wbig : wsml;
    const float* bias = big ? bbig : bsml;

    int lm = tid >> 2;                   // act-load row 0..63
    int lq = tid & 3;                    // act-load k quad
    int wk = tid >> 4;                   // w-load k row 0..15
    int wc = (tid & 15) * 4;             // w-load col offset

    int tm = tid >> 4;                   // 0..15 : rows tm*4..+3
    int tn = tid & 15;                   // 0..15 : cols tn*4..+3

    const float* hrow;
    if (GATHER) {
        int b = borig[r0 + lm];
        hrow = (b >= 0) ? &in[(size_t)b * K] : (const float*)0;
    } else {
        hrow = &in[(size_t)(r0 + lm) * K];   // pad rows hold garbage; harmless
    }

    float acc[4][4];
    #pragma unroll
    for (int i = 0; i < 4; ++i)
        #pragma unroll
        for (int j = 0; j < 4; ++j) acc[i][j] = 0.f;

    for (int k0 = 0; k0 < K; k0 += 16) {
        float4 hv = make_float4(0.f, 0.f, 0.f, 0.f);
        if (!GATHER || hrow) hv = *(const float4*)&hrow[k0 + lq * 4];
        float4 wv = *(const float4*)&w[(size_t)(k0 + wk) * DOUT + cb + wc];
        __syncthreads();
        hs[lq * 4 + 0][lm] = hv.x;
        hs[lq * 4 + 1][lm] = hv.y;
        hs[lq * 4 + 2][lm] = hv.z;
        hs[lq * 4 + 3][lm] = hv.w;
        *(float4*)&wt[wk][wc] = wv;
        __syncthreads();
        #pragma unroll
        for (int kk = 0; kk < 16; ++kk) {
            float4 a  = *(const float4*)&hs[kk][tm * 4];
            float4 bf = *(const float4*)&wt[kk][tn * 4];
            acc[0][0] = fmaf(a.x, bf.x, acc[0][0]);
            acc[0][1] = fmaf(a.x, bf.y, acc[0][1]);
            acc[0][2] = fmaf(a.x, bf.z, acc[0][2]);
            acc[0][3] = fmaf(a.x, bf.w, acc[0][3]);
            acc[1][0] = fmaf(a.y, bf.x, acc[1][0]);
            acc[1][1] = fmaf(a.y, bf.y, acc[1][1]);
            acc[1][2] = fmaf(a.y, bf.z, acc[1][2]);
            acc[1][3] = fmaf(a.y, bf.w, acc[1][3]);
            acc[2][0] = fmaf(a.z, bf.x, acc[2][0]);
            acc[2][1] = fmaf(a.z, bf.y, acc[2][1]);
            acc[2][2] = fmaf(a.z, bf.z, acc[2][2]);
            acc[2][3] = fmaf(a.z, bf.w, acc[2][3]);
            acc[3][0] = fmaf(a.w, bf.x, acc[3][0]);
            acc[3][1] = fmaf(a.w, bf.y, acc[3][1]);
            acc[3][2] = fmaf(a.w, bf.z, acc[3][2]);
            acc[3][3] = fmaf(a.w, bf.w, acc[3][3]);
        }
    }

    float4 bv = *(const float4*)&bias[cb + tn * 4];
    #pragma unroll
    for (int i = 0; i < 4; ++i) {
        float o[4];
        o[0] = fmaxf(acc[i][0] + bv.x, 0.f);
        o[1] = fmaxf(acc[i][1] + bv.y, 0.f);
        o[2] = fmaxf(acc[i][2] + bv.z, 0.f);
        o[3] = fmaxf(acc[i][3] + bv.w, 0.f);
        if (SPLIT) {
            // element (row, k): frag addr = ((by*32+kk)*3+limb)*2048 + m*512
            //                               + (lg*16 + l15)*8 + j   [shorts]
            int row = r0 + tm * 4 + i;
            int by_ = row >> 6, rl = row & 63;
            int mfr = rl >> 4, p15 = rl & 15;
            int kt  = cb + tn * 4;           // 4 consecutive k, same lg group
            int kk  = kt >> 5, lgk = (kt >> 3) & 3, j0 = kt & 7;
            size_t base = (size_t)(by_ * 32 + kk) * 6144 + (size_t)mfr * 512
                        + (size_t)(lgk * 16 + p15) * 8 + j0;
            ushort4 s0, s1, s2;
            unsigned short* q0[4] = {&s0.x, &s0.y, &s0.z, &s0.w};
            unsigned short* q1[4] = {&s1.x, &s1.y, &s1.z, &s1.w};
            unsigned short* q2[4] = {&s2.x, &s2.y, &s2.z, &s2.w};
            #pragma unroll
            for (int j = 0; j < 4; ++j) {
                unsigned short a0 = f2bf(o[j]);
                float r1v = o[j] - bf2f(a0);
                unsigned short a1 = f2bf(r1v);
                float r2v = r1v - bf2f(a1);
                *q0[j] = a0; *q1[j] = a1; *q2[j] = f2bf(r2v);
            }
            *(ushort4*)&hbA[base]        = s0;
            *(ushort4*)&hbA[base + 2048] = s1;
            *(ushort4*)&hbA[base + 4096] = s2;
        } else {
            float4 ov;
            ov.x = o[0]; ov.y = o[1]; ov.z = o[2]; ov.w = o[3];
            *(float4*)&out[(size_t)(r0 + tm * 4 + i) * DOUT + cb + tn * 4] = ov;
        }
    }
}

// ---------------- kernel 2: bf16x3 MFMA DIFF-GEMM, zero-LDS + 2-deep pipeline
// Round-6 failure: serial chain {issue 16 B-loads -> drain -> split -> MFMA}
// exposed ~900cy HBM latency per K-step (MfmaUtil 21 / VALU 31 / HBM 17%).
// Fix: double-buffered raw-B registers; LOADB(kk+1) issues BEFORE STEP(kk)'s
// split+MFMA (~880cy of work between issue and use). A-frag loads (L2/L3-hot
// hbA) issue at STEP-top and land under the split VALU. No LDS, no barriers.
// Macros (not lambdas/arrays-by-pointer) keep all buffer indices compile-time
// so everything stays in registers (rule: runtime-indexed arrays -> scratch).
__global__ __launch_bounds__(256, 3) void k2_mfma(
    const unsigned short* __restrict__ hbA,
    const float* __restrict__ bw3, const float* __restrict__ bb3,
    const float* __restrict__ sw3, const float* __restrict__ sb3,
    const float* __restrict__ gum,
    const int* __restrict__ meta, const int* __restrict__ borig,
    unsigned char* __restrict__ bits) {
    int tid = threadIdx.x;
    int wgid = blockIdx.x;              // 0..2303
    int xr  = wgid & 7;
    int s_  = wgid >> 3;
    int by  = s_ % 9;                   // row tile 0..8
    int q   = s_ / 9;                   // col chunk 0..31
    int bx  = q * 8 + xr;               // col tile 0..255 (XCD-local col ownership)
    if (bx >= 255) return;              // no barriers -> early exit trivially safe

    int r0 = by * 64;
    int db = bx * 128;                  // diff (e-pair) column base
    int S = meta[0];
    bool big = (r0 < S);
    const float* w3 = big ? bw3 : sw3;
    const float* b3 = big ? bb3 : sb3;

    int lane = tid & 63;
    int wid  = tid >> 6;                // wave 0..3 -> diff cols wid*32..+31
    int l15  = lane & 15;
    int lg   = lane >> 4;               // k-group 0..3

    int colg0 = db + wid * 32 + l15;    // this lane's n=0 diff column

    f32x4 acc[4][2];
    #pragma unroll
    for (int m = 0; m < 4; ++m)
        #pragma unroll
        for (int n = 0; n < 2; ++n) acc[m][n] = (f32x4)0.f;

    const unsigned short* ap0 = hbA + (size_t)(by * 32) * 6144 + (size_t)lane * 8;
    const float* wbase = w3 + (size_t)(lg * 8) * OUTCOLS + 2 * (size_t)colg0;

#define LOADB(BUF, KK) do {                                                     \
    const float* wp_ = wbase + (size_t)(KK) * 32 * OUTCOLS;                     \
    _Pragma("unroll")                                                           \
    for (int n_ = 0; n_ < 2; ++n_) {                                            \
        _Pragma("unroll")                                                       \
        for (int j_ = 0; j_ < 8; ++j_)                                          \
            BUF[n_ * 8 + j_] = *(const float2*)(wp_ + (size_t)j_ * OUTCOLS      \
                                                + n_ * 32);                     \
    }                                                                           \
} while (0)

#define STEP(BUF, KK) do {                                                      \
    const unsigned short* ap_ = ap0 + (size_t)(KK) * 6144;                      \
    bf16x8 af_[3][4];                                                           \
    _Pragma("unroll")                                                           \
    for (int l_ = 0; l_ < 3; ++l_)                                              \
        _Pragma("unroll")                                                       \
        for (int m_ = 0; m_ < 4; ++m_)                                          \
            af_[l_][m_] = *(const bf16x8*)(ap_ + l_ * 2048 + m_ * 512);         \
    _Pragma("unroll")                                                           \
    for (int n_ = 0; n_ < 2; ++n_) {                                            \
        u32x4 f0_, f1_, f2_;                                                    \
        _Pragma("unroll")                                                       \
        for (int w_ = 0; w_ < 4; ++w_) {                                        \
            float dA_ = BUF[n_ * 8 + 2 * w_].x     - BUF[n_ * 8 + 2 * w_].y;    \
            float dB_ = BUF[n_ * 8 + 2 * w_ + 1].x - BUF[n_ * 8 + 2 * w_ + 1].y;\
            unsigned short aL_ = f2bf(dA_), aH_ = f2bf(dB_);                    \
            f0_[w_] = (unsigned int)aL_ | ((unsigned int)aH_ << 16);            \
            float rA_ = dA_ - bf2f(aL_), rB_ = dB_ - bf2f(aH_);                 \
            unsigned short bL_ = f2bf(rA_), bH_ = f2bf(rB_);                    \
            f1_[w_] = (unsigned int)bL_ | ((unsigned int)bH_ << 16);            \
            float sA_ = rA_ - bf2f(bL_), sB_ = rB_ - bf2f(bH_);                 \
            f2_[w_] = (unsigned int)f2bf(sA_) | ((unsigned int)f2bf(sB_) << 16);\
        }                                                                       \
        bf16x8 b0_ = __builtin_bit_cast(bf16x8, f0_);                           \
        bf16x8 b1_ = __builtin_bit_cast(bf16x8, f1_);                           \
        bf16x8 b2_ = __builtin_bit_cast(bf16x8, f2_);                           \
        _Pragma("unroll")                                                       \
        for (int m_ = 0; m_ < 4; ++m_) {                                        \
            f32x4 c_ = acc[m_][n_];                                             \
            c_ = __builtin_amdgcn_mfma_f32_16x16x32_bf16(af_[0][m_], b0_, c_, 0, 0, 0); \
            c_ = __builtin_amdgcn_mfma_f32_16x16x32_bf16(af_[0][m_], b1_, c_, 0, 0, 0); \
            c_ = __builtin_amdgcn_mfma_f32_16x16x32_bf16(af_[1][m_], b0_, c_, 0, 0, 0); \
            c_ = __builtin_amdgcn_mfma_f32_16x16x32_bf16(af_[1][m_], b1_, c_, 0, 0, 0); \
            c_ = __builtin_amdgcn_mfma_f32_16x16x32_bf16(af_[0][m_], b2_, c_, 0, 0, 0); \
            c_ = __builtin_amdgcn_mfma_f32_16x16x32_bf16(af_[2][m_], b0_, c_, 0, 0, 0); \
            acc[m_][n_] = c_;                                                   \
        }                                                                       \
    }                                                                           \
} while (0)

    float2 brE[16], brO[16];
    LOADB(brE, 0);
    for (int ki = 0; ki < 16; ++ki) {
        int ke = ki * 2;
        LOADB(brO, ke + 1);             // prefetch odd step while even computes
        STEP(brE, ke);
        LOADB(brE, (ki < 15) ? ke + 2 : 31);   // last iter: harmless re-load
        STEP(brO, ke + 1);
    }
#undef LOADB
#undef STEP

    // ---- epilogue: bias-diff + gumbel-diff, compare, store bit bytes ----
    #pragma unroll
    for (int n = 0; n < 2; ++n) {
        int colg = db + wid * 32 + n * 16 + l15;     // global e-pair index
        float2 bv = *(const float2*)&b3[2 * colg];
        float bd = bv.x - bv.y;
        #pragma unroll
        for (int m = 0; m < 4; ++m) {
            #pragma unroll
            for (int r = 0; r < 4; ++r) {
                int slot = r0 + m * 16 + lg * 4 + r;
                int b = borig[slot];
                if (b < 0) continue;
                float2 gv = *(const float2*)&gum[(size_t)b * OUTCOLS + 2 * colg];
                float g = acc[m][n][r] + bd + (gv.x - gv.y);
                bits[(size_t)b * E_PAIRS + colg] = (g >= 0.f) ? 1 : 0;
            }
        }
    }
}

// ---------------- kernel 3: tiled bit->fp32 expansion with LDS transpose ------
__global__ __launch_bounds__(256) void k3_expand(
    const unsigned char* __restrict__ bits, float* __restrict__ out) {
    __shared__ unsigned char L[64][68];   // stride 68 bytes
    const int ti_tab[10] = {0,0,0,0,1,1,1,2,2,3};
    const int tj_tab[10] = {0,1,2,3,1,2,3,2,3,3};
    int p = blockIdx.x;                   // 0..9
    int b = blockIdx.y;                   // 0..511
    int ti = ti_tab[p], tj = tj_tab[p];
    int t = threadIdx.x;

    // ---- stage bits: row r (i = ti*64+r), 16 bytes per thread ----
    {
        int r = t >> 2;                   // 0..63
        int q = t & 3;                    // 0..3
        int i = ti * 64 + r;
        // e(i,j) = i*(511-i)/2 + j - i - 1  (valid for j > i)
        long base = (long)b * E_PAIRS + (long)i * (511 - i) / 2 - i - 1;
        int j0 = tj * 64 + q * 16;
        #pragma unroll
        for (int k = 0; k < 16; ++k) {
            int j = j0 + k;
            unsigned char v = (j > i) ? bits[base + j] : (unsigned char)0;
            L[r][q * 16 + k] = v;
        }
    }
    __syncthreads();

    int h  = t >> 4;                      // 0..15  (row within group of 16)
    int w4 = (t & 15) * 4;                // col base, float4 granularity

    // ---- direct tile: out[b][ti*64+ii][tj*64 + w4 .. +3] ----
    {
        #pragma unroll
        for (int rr = 0; rr < 4; ++rr) {
            int ii = rr * 16 + h;
            int i_ = ti * 64 + ii;
            float4 v;
            if (ti == tj) {
                int jj;
                jj = w4 + 0; v.x = (jj > ii) ? (float)L[ii][jj] : (jj < ii ? (float)L[jj][ii] : 0.f);
                jj = w4 + 1; v.y = (jj > ii) ? (float)L[ii][jj] : (jj < ii ? (float)L[jj][ii] : 0.f);
                jj = w4 + 2; v.z = (jj > ii) ? (float)L[ii][jj] : (jj < ii ? (float)L[jj][ii] : 0.f);
                jj = w4 + 3; v.w = (jj > ii) ? (float)L[ii][jj] : (jj < ii ? (float)L[jj][ii] : 0.f);
            } else {
                v.x = (float)L[ii][w4 + 0];
                v.y = (float)L[ii][w4 + 1];
                v.z = (float)L[ii][w4 + 2];
                v.w = (float)L[ii][w4 + 3];
            }
            size_t o = (((size_t)b * 256 + i_) * 256) + tj * 64 + w4;
            *(float4*)&out[o] = v;
        }
    }

    // ---- mirrored tile (off-diagonal only): out[b][tj*64+jj][ti*64 + w4 ..] ----
    if (ti != tj) {
        #pragma unroll
        for (int rr = 0; rr < 4; ++rr) {
            int jj = rr * 16 + h;
            int j_ = tj * 64 + jj;
            float4 v;                      // value(i=col, j=row) = L[col_local][jj]
            v.x = (float)L[w4 + 0][jj];
            v.y = (float)L[w4 + 1][jj];
            v.z = (float)L[w4 + 2][jj];
            v.w = (float)L[w4 + 3][jj];
            size_t o = (((size_t)b * 256 + j_) * 256) + ti * 64 + w4;
            *(float4*)&out[o] = v;
        }
    }
}

// -----------------------------------------------------------------------------
extern "C" void kernel_launch(void* const* d_in, const int* in_sizes, int n_in,
                              void* d_out, int out_size, void* d_ws, size_t ws_size,
                              hipStream_t stream) {
    const float* x   = (const float*)d_in[0];
    const float* gum = (const float*)d_in[1];
    const float* bw0 = (const float*)d_in[2];  const float* bb0 = (const float*)d_in[3];
    const float* sw0 = (const float*)d_in[4];  const float* sb0 = (const float*)d_in[5];
    const float* bw1 = (const float*)d_in[6];  const float* bb1 = (const float*)d_in[7];
    const float* sw1 = (const float*)d_in[8];  const float* sb1 = (const float*)d_in[9];
    const float* bw2 = (const float*)d_in[10]; const float* bb2 = (const float*)d_in[11];
    const float* sw2 = (const float*)d_in[12]; const float* sb2 = (const float*)d_in[13];
    const float* bw3 = (const float*)d_in[14]; const float* bb3 = (const float*)d_in[15];
    const float* sw3 = (const float*)d_in[16]; const float* sb3 = (const float*)d_in[17];

    char* ws = (char*)d_ws;
    int*   meta  = (int*)ws;                               // 64 B
    int*   borig = (int*)(ws + 64);                        // 576 ints
    float* act1  = (float*)(ws + 4096);                    // 576*256 fp32
    float* act2  = (float*)(ws + 593920);                  // 576*512 fp32
    unsigned short* hbA = (unsigned short*)(ws + 1773568); // 576*1024*3 bf16 frag-order
    unsigned char* bits = (unsigned char*)(ws + 5312512);  // 512*32640 bytes
    float* out = (float*)d_out;                            // total ws use ~22.0 MB

    k0_sort<<<1, SLOTS, 0, stream>>>(x, meta, borig);
    k1_gemm<true,  COND, D1, false><<<dim3(9, D1 / 64), 256, 0, stream>>>(
        x,    bw0, bb0, sw0, sb0, meta, borig, act1, 0);
    k1_gemm<false, D1,   D2, false><<<dim3(9, D2 / 64), 256, 0, stream>>>(
        act1, bw1, bb1, sw1, sb1, meta, borig, act2, 0);
    k1_gemm<false, D2,   D3, true><<<dim3(9, D3 / 64), 256, 0, stream>>>(
        act2, bw2, bb2, sw2, sb2, meta, borig, (float*)0, hbA);
    k2_mfma<<<2304, 256, 0, stream>>>(hbA, bw3, bb3, sw3, sb3, gum,
                                      meta, borig, bits);
    k3_expand<<<dim3(10, BATCH), 256, 0, stream>>>(bits, out);
}